// Round 1
// baseline (14638.036 us; speedup 1.0000x reference)
//
#include <hip/hip_runtime.h>
#include <hip/hip_bf16.h>

#define N_NODES 20000
#define N_EDGES 320000
#define T_STEPS 64
#define F_IN    16
#define HGd     128
#define HTd     256
#define INVN    (1.0f/20000.0f)

// ---------------- init ----------------
__global__ void k_zero(int* __restrict__ deg, float* __restrict__ Hg) {
    int i = blockIdx.x * blockDim.x + threadIdx.x;
    if (i < N_NODES) deg[i] = 0;
    if (i < T_STEPS * HGd) Hg[i] = 0.0f;
}

__global__ void k_degree(const int* __restrict__ ei, int* __restrict__ deg) {
    int e = blockIdx.x * blockDim.x + threadIdx.x;
    if (e < N_EDGES) atomicAdd(&deg[ei[N_EDGES + e]], 1);
}

__global__ __launch_bounds__(1024) void k_scan(const int* __restrict__ deg,
        int* __restrict__ rp, int* __restrict__ cursor, float* __restrict__ invd) {
    __shared__ int sh[1024];
    __shared__ int carry_s;
    int tid = threadIdx.x;
    if (tid == 0) { carry_s = 0; rp[0] = 0; }
    __syncthreads();
    for (int base = 0; base < N_NODES; base += 1024) {
        int i = base + tid;
        int v = (i < N_NODES) ? deg[i] : 0;
        sh[tid] = v;
        __syncthreads();
        for (int off = 1; off < 1024; off <<= 1) {
            int t = (tid >= off) ? sh[tid - off] : 0;
            __syncthreads();
            sh[tid] += t;
            __syncthreads();
        }
        int inc = sh[tid] + carry_s;
        if (i < N_NODES) {
            rp[i + 1] = inc;
            cursor[i] = inc - v;
            invd[i] = (v > 0) ? (1.0f / (float)v) : 0.0f;
        }
        __syncthreads();
        if (tid == 1023) carry_s = inc;
        __syncthreads();
    }
}

__global__ void k_fill(const int* __restrict__ ei, int* __restrict__ cursor,
                       int* __restrict__ csr) {
    int e = blockIdx.x * blockDim.x + threadIdx.x;
    if (e < N_EDGES) {
        int d = ei[N_EDGES + e];
        int p = atomicAdd(&cursor[d], 1);
        csr[p] = ei[e];
    }
}

// ---------------- weight prep (k-major transposes) ----------------
// Wc1[k][o]: k<16 -> W1l[o][k], else W1r[o][k-16]     (32 x 128)
// Wc2[k][o]: k<128 -> W2l[o][k], else W2r[o][k-128]   (256 x 128)
// WihT[k][g] = W_ih[g][k]                             (128 x 768)
// WhhT[k][g] = W_hh[g][k]                             (256 x 768)
__global__ void k_prepw(const float* __restrict__ W1l, const float* __restrict__ W1r,
                        const float* __restrict__ W2l, const float* __restrict__ W2r,
                        const float* __restrict__ W_ih, const float* __restrict__ W_hh,
                        float* __restrict__ Wc1, float* __restrict__ Wc2,
                        float* __restrict__ WihT, float* __restrict__ WhhT) {
    int i = blockIdx.x * blockDim.x + threadIdx.x;
    const int n1 = 32 * 128, n2 = 256 * 128, n3 = 128 * 768, n4 = 256 * 768;
    if (i < n1) {
        int k = i >> 7, o = i & 127;
        Wc1[i] = (k < 16) ? W1l[o * 16 + k] : W1r[o * 16 + (k - 16)];
    } else if (i < n1 + n2) {
        int j = i - n1; int k = j >> 7, o = j & 127;
        Wc2[j] = (k < 128) ? W2l[o * 128 + k] : W2r[o * 128 + (k - 128)];
    } else if (i < n1 + n2 + n3) {
        int j = i - n1 - n2; int k = j / 768, g = j % 768;
        WihT[j] = W_ih[g * 128 + k];
    } else if (i < n1 + n2 + n3 + n4) {
        int j = i - n1 - n2 - n3; int k = j / 768, g = j % 768;
        WhhT[j] = W_hh[g * 256 + k];
    }
}

// ---------------- SAGE layer 1 (one timestep) ----------------
// h1[n][o] = relu( mean_agg(x)[n] @ W1l.T + b1l + x[n] @ W1r.T )
#define NB1 64
__global__ __launch_bounds__(256) void k_sage1(
        const float* __restrict__ xt, const int* __restrict__ rp,
        const int* __restrict__ csr, const float* __restrict__ invd,
        const float* __restrict__ Wc1, const float* __restrict__ b1l,
        float* __restrict__ h1) {
    __shared__ float u[NB1][32];    // [node][k]  k: 0..15 agg, 16..31 root
    __shared__ float w[32][128];    // k-major weights
    int tid = threadIdx.x;
    int nbase = blockIdx.x * NB1;

    for (int i = tid; i < 32 * 128; i += 256) ((float*)w)[i] = Wc1[i];

    { // phase 1: aggregation, 4 threads per node (float4 per thread)
        int n = tid >> 2, q = tid & 3;
        int node = nbase + n;
        float4 acc = make_float4(0, 0, 0, 0);
        float4 root = make_float4(0, 0, 0, 0);
        if (node < N_NODES) {
            int s = rp[node], e = rp[node + 1];
            for (int i = s; i < e; ++i) {
                int sn = csr[i];
                float4 v = *reinterpret_cast<const float4*>(xt + sn * F_IN + q * 4);
                acc.x += v.x; acc.y += v.y; acc.z += v.z; acc.w += v.w;
            }
            float id = invd[node];
            acc.x *= id; acc.y *= id; acc.z *= id; acc.w *= id;
            root = *reinterpret_cast<const float4*>(xt + node * F_IN + q * 4);
        }
        *reinterpret_cast<float4*>(&u[n][q * 4]) = acc;
        *reinterpret_cast<float4*>(&u[n][16 + q * 4]) = root;
    }
    __syncthreads();

    // phase 2: GEMM  [64 nodes x 32 k] @ [32 k x 128 o]; thread tile 8 nodes x 4 outs
    int og = tid & 31, ng = tid >> 5;
    int o = og * 4;
    float acc[8][4];
#pragma unroll
    for (int j = 0; j < 8; ++j)
#pragma unroll
        for (int c = 0; c < 4; ++c) acc[j][c] = 0.0f;

#pragma unroll
    for (int k = 0; k < 32; k += 4) {
        float4 w0 = *reinterpret_cast<const float4*>(&w[k + 0][o]);
        float4 w1 = *reinterpret_cast<const float4*>(&w[k + 1][o]);
        float4 w2 = *reinterpret_cast<const float4*>(&w[k + 2][o]);
        float4 w3 = *reinterpret_cast<const float4*>(&w[k + 3][o]);
#pragma unroll
        for (int j = 0; j < 8; ++j) {
            float4 uv = *reinterpret_cast<const float4*>(&u[ng * 8 + j][k]);
            acc[j][0] += uv.x * w0.x + uv.y * w1.x + uv.z * w2.x + uv.w * w3.x;
            acc[j][1] += uv.x * w0.y + uv.y * w1.y + uv.z * w2.y + uv.w * w3.y;
            acc[j][2] += uv.x * w0.z + uv.y * w1.z + uv.z * w2.z + uv.w * w3.z;
            acc[j][3] += uv.x * w0.w + uv.y * w1.w + uv.z * w2.w + uv.w * w3.w;
        }
    }

    float4 bv = *reinterpret_cast<const float4*>(b1l + o);
#pragma unroll
    for (int j = 0; j < 8; ++j) {
        int node = nbase + ng * 8 + j;
        if (node < N_NODES) {
            float4 r;
            r.x = fmaxf(acc[j][0] + bv.x, 0.0f);
            r.y = fmaxf(acc[j][1] + bv.y, 0.0f);
            r.z = fmaxf(acc[j][2] + bv.z, 0.0f);
            r.w = fmaxf(acc[j][3] + bv.w, 0.0f);
            *reinterpret_cast<float4*>(h1 + node * HGd + o) = r;
        }
    }
}

// ---------------- SAGE layer 2 + node-mean reduce (one timestep) ----------------
#define NB2 32
__global__ __launch_bounds__(256) void k_sage2(
        const float* __restrict__ h1, const int* __restrict__ rp,
        const int* __restrict__ csr, const float* __restrict__ invd,
        const float* __restrict__ Wc2, const float* __restrict__ b2l,
        float* __restrict__ HgT) {
    __shared__ float u[NB2][256];   // [node][k]  k: 0..127 agg, 128..255 root (32KB)
    __shared__ float wt[64][128];   // weight k-tile (32KB)
    __shared__ float red[8][128];   // cross-group reduction (4KB)
    int tid = threadIdx.x;
    int nbase = blockIdx.x * NB2;   // N_NODES % NB2 == 0

    { // phase 1: half-wave per node, lanes cover 128 floats as float4
        int hw = tid >> 5;          // 0..7
        int l = tid & 31;
        for (int nn = 0; nn < 4; ++nn) {
            int n = hw * 4 + nn;
            int node = nbase + n;
            int s = rp[node], e = rp[node + 1];
            float4 a = make_float4(0, 0, 0, 0);
            for (int i = s; i < e; ++i) {
                int sn = csr[i];
                float4 v = *reinterpret_cast<const float4*>(h1 + sn * HGd + l * 4);
                a.x += v.x; a.y += v.y; a.z += v.z; a.w += v.w;
            }
            float id = invd[node];
            a.x *= id; a.y *= id; a.z *= id; a.w *= id;
            *reinterpret_cast<float4*>(&u[n][l * 4]) = a;
            float4 r = *reinterpret_cast<const float4*>(h1 + node * HGd + l * 4);
            *reinterpret_cast<float4*>(&u[n][128 + l * 4]) = r;
        }
    }
    __syncthreads();

    // phase 2: GEMM [32 nodes x 256 k] @ [256 k x 128 o]; thread tile 4 nodes x 4 outs
    int og = tid & 31, ng = tid >> 5;
    int o = og * 4;
    float acc[4][4];
#pragma unroll
    for (int j = 0; j < 4; ++j)
#pragma unroll
        for (int c = 0; c < 4; ++c) acc[j][c] = 0.0f;

    for (int kt = 0; kt < 256; kt += 64) {
        for (int i = tid; i < 64 * 128; i += 256) ((float*)wt)[i] = Wc2[kt * 128 + i];
        __syncthreads();
#pragma unroll
        for (int kk = 0; kk < 64; kk += 4) {
            float4 w0 = *reinterpret_cast<const float4*>(&wt[kk + 0][o]);
            float4 w1 = *reinterpret_cast<const float4*>(&wt[kk + 1][o]);
            float4 w2 = *reinterpret_cast<const float4*>(&wt[kk + 2][o]);
            float4 w3 = *reinterpret_cast<const float4*>(&wt[kk + 3][o]);
#pragma unroll
            for (int j = 0; j < 4; ++j) {
                float4 uv = *reinterpret_cast<const float4*>(&u[ng * 4 + j][kt + kk]);
                acc[j][0] += uv.x * w0.x + uv.y * w1.x + uv.z * w2.x + uv.w * w3.x;
                acc[j][1] += uv.x * w0.y + uv.y * w1.y + uv.z * w2.y + uv.w * w3.y;
                acc[j][2] += uv.x * w0.z + uv.y * w1.z + uv.z * w2.z + uv.w * w3.z;
                acc[j][3] += uv.x * w0.w + uv.y * w1.w + uv.z * w2.w + uv.w * w3.w;
            }
        }
        __syncthreads();
    }

    // phase 3: bias + relu + sum over this block's 32 nodes -> atomic into Hg[t]
    float4 bv = *reinterpret_cast<const float4*>(b2l + o);
    float part[4] = {0, 0, 0, 0};
#pragma unroll
    for (int j = 0; j < 4; ++j) {
        part[0] += fmaxf(acc[j][0] + bv.x, 0.0f);
        part[1] += fmaxf(acc[j][1] + bv.y, 0.0f);
        part[2] += fmaxf(acc[j][2] + bv.z, 0.0f);
        part[3] += fmaxf(acc[j][3] + bv.w, 0.0f);
    }
#pragma unroll
    for (int c = 0; c < 4; ++c) red[ng][o + c] = part[c];
    __syncthreads();
    if (ng == 0) {
#pragma unroll
        for (int c = 0; c < 4; ++c) {
            float tot = 0.0f;
#pragma unroll
            for (int g = 0; g < 8; ++g) tot += red[g][o + c];
            atomicAdd(&HgT[o + c], tot);
        }
    }
}

// ---------------- GRU input gates for all timesteps ----------------
__global__ __launch_bounds__(768) void k_gi(const float* __restrict__ Hg,
        const float* __restrict__ WihT, const float* __restrict__ b_ih,
        float* __restrict__ gi_all) {
    __shared__ float x[HGd];
    int t = blockIdx.x, g = threadIdx.x;
    if (g < HGd) x[g] = Hg[t * HGd + g] * INVN;
    __syncthreads();
    float a = b_ih[g];
    for (int k = 0; k < HGd; ++k) a += WihT[k * 768 + g] * x[k];
    gi_all[t * 768 + g] = a;
}

// ---------------- sequential GRU + head ----------------
__global__ __launch_bounds__(768) void k_gru(const float* __restrict__ gi_all,
        const float* __restrict__ WhhT, const float* __restrict__ b_hh,
        const float* __restrict__ Wh1, const float* __restrict__ bh1,
        const float* __restrict__ Wh2, const float* __restrict__ bh2,
        float* __restrict__ out) {
    __shared__ float h[HTd];
    __shared__ float gh[3 * HTd];
    int g = threadIdx.x;
    if (g < HTd) h[g] = 0.0f;
    __syncthreads();
    float bh = b_hh[g];
    for (int t = 0; t < T_STEPS; ++t) {
        float a = bh;
#pragma unroll 8
        for (int k = 0; k < HTd; ++k) a += WhhT[k * 768 + g] * h[k];
        gh[g] = a;
        __syncthreads();
        if (g < HTd) {
            float gir = gi_all[t * 768 + g];
            float giz = gi_all[t * 768 + HTd + g];
            float gin = gi_all[t * 768 + 2 * HTd + g];
            float r = 1.0f / (1.0f + expf(-(gir + gh[g])));
            float z = 1.0f / (1.0f + expf(-(giz + gh[HTd + g])));
            float n = tanhf(gin + r * gh[2 * HTd + g]);
            h[g] = (1.0f - z) * n + z * h[g];
        }
        __syncthreads();
    }
    __shared__ float act[64];
    if (g < 64) {
        float a = bh1[g];
        const float* wr = Wh1 + g * HTd;
        for (int k = 0; k < HTd; ++k) a += wr[k] * h[k];
        act[g] = fmaxf(a, 0.0f);
    }
    __syncthreads();
    if (g == 0) {
        float y = bh2[0];
        for (int j = 0; j < 64; ++j) y += Wh2[j] * act[j];
        out[0] = y;
    }
}

// ---------------- launch ----------------
extern "C" void kernel_launch(void* const* d_in, const int* in_sizes, int n_in,
                              void* d_out, int out_size, void* d_ws, size_t ws_size,
                              hipStream_t stream) {
    const float* x_seq = (const float*)d_in[0];
    const int*   ei    = (const int*)d_in[1];
    const float* W1l   = (const float*)d_in[2];
    const float* b1l   = (const float*)d_in[3];
    const float* W1r   = (const float*)d_in[4];
    const float* W2l   = (const float*)d_in[5];
    const float* b2l   = (const float*)d_in[6];
    const float* W2r   = (const float*)d_in[7];
    const float* W_ih  = (const float*)d_in[8];
    const float* W_hh  = (const float*)d_in[9];
    const float* b_ih  = (const float*)d_in[10];
    const float* b_hh  = (const float*)d_in[11];
    const float* Wh1   = (const float*)d_in[12];
    const float* bh1   = (const float*)d_in[13];
    const float* Wh2   = (const float*)d_in[14];
    const float* bh2   = (const float*)d_in[15];
    float* out = (float*)d_out;

    char* ws = (char*)d_ws;
    size_t off = 0;
    auto take = [&](size_t nbytes) -> void* {
        void* p = (void*)(ws + off);
        off += (nbytes + 255) & ~(size_t)255;
        return p;
    };
    int*   deg     = (int*)take(N_NODES * 4);
    int*   rp      = (int*)take((N_NODES + 1) * 4);
    int*   cursor  = (int*)take(N_NODES * 4);
    int*   csr     = (int*)take(N_EDGES * 4);
    float* invd    = (float*)take(N_NODES * 4);
    float* Wc1     = (float*)take(32 * 128 * 4);
    float* Wc2     = (float*)take(256 * 128 * 4);
    float* WihT    = (float*)take(128 * 768 * 4);
    float* WhhT    = (float*)take(256 * 768 * 4);
    float* Hg      = (float*)take(T_STEPS * HGd * 4);
    float* gi_all  = (float*)take(T_STEPS * 768 * 4);
    float* h1      = (float*)take((size_t)N_NODES * HGd * 4);

    k_zero<<<(N_NODES + 255) / 256, 256, 0, stream>>>(deg, Hg);
    k_degree<<<(N_EDGES + 255) / 256, 256, 0, stream>>>(ei, deg);
    k_scan<<<1, 1024, 0, stream>>>(deg, rp, cursor, invd);
    k_fill<<<(N_EDGES + 255) / 256, 256, 0, stream>>>(ei, cursor, csr);
    {
        int total = 32 * 128 + 256 * 128 + 128 * 768 + 256 * 768;
        k_prepw<<<(total + 255) / 256, 256, 0, stream>>>(W1l, W1r, W2l, W2r, W_ih, W_hh,
                                                         Wc1, Wc2, WihT, WhhT);
    }
    for (int t = 0; t < T_STEPS; ++t) {
        const float* xt = x_seq + (size_t)t * N_NODES * F_IN;
        k_sage1<<<(N_NODES + NB1 - 1) / NB1, 256, 0, stream>>>(xt, rp, csr, invd, Wc1, b1l, h1);
        k_sage2<<<N_NODES / NB2, 256, 0, stream>>>(h1, rp, csr, invd, Wc2, b2l, Hg + t * HGd);
    }
    k_gi<<<T_STEPS, 768, 0, stream>>>(Hg, WihT, b_ih, gi_all);
    k_gru<<<1, 768, 0, stream>>>(gi_all, WhhT, b_hh, Wh1, bh1, Wh2, bh2, out);
}

// Round 2
// 7592.937 us; speedup vs baseline: 1.9278x; 1.9278x over previous
//
#include <hip/hip_runtime.h>
#include <hip/hip_bf16.h>

#define N_NODES 20000
#define N_EDGES 320000
#define T_STEPS 64
#define F_IN    16
#define HGd     128
#define HTd     256
#define INVN    (1.0f/20000.0f)
#define GRU_BLOCKS 24

typedef __attribute__((ext_vector_type(8))) short short8;
typedef __attribute__((ext_vector_type(4))) float f32x4;

static __device__ __forceinline__ ushort f2bf(float f) {
    __hip_bfloat16 b = __float2bfloat16(f);
    return *reinterpret_cast<ushort*>(&b);
}
static __device__ __forceinline__ float bflo(uint v) { return __uint_as_float(v << 16); }
static __device__ __forceinline__ float bfhi(uint v) { return __uint_as_float(v & 0xffff0000u); }

// ---------------- init ----------------
__global__ void k_zero(int* __restrict__ deg, float* __restrict__ Hg, int* __restrict__ cnt) {
    int i = blockIdx.x * blockDim.x + threadIdx.x;
    if (i < N_NODES) deg[i] = 0;
    if (i < T_STEPS * HGd) Hg[i] = 0.0f;
    if (i == 0) *cnt = 0;
}

__global__ void k_degree(const int* __restrict__ ei, int* __restrict__ deg) {
    int e = blockIdx.x * blockDim.x + threadIdx.x;
    if (e < N_EDGES) atomicAdd(&deg[ei[N_EDGES + e]], 1);
}

__global__ __launch_bounds__(1024) void k_scan(const int* __restrict__ deg,
        int* __restrict__ rp, int* __restrict__ cursor, float* __restrict__ invd) {
    __shared__ int sh[1024];
    __shared__ int carry_s;
    int tid = threadIdx.x;
    if (tid == 0) { carry_s = 0; rp[0] = 0; }
    __syncthreads();
    for (int base = 0; base < N_NODES; base += 1024) {
        int i = base + tid;
        int v = (i < N_NODES) ? deg[i] : 0;
        sh[tid] = v;
        __syncthreads();
        for (int off = 1; off < 1024; off <<= 1) {
            int t = (tid >= off) ? sh[tid - off] : 0;
            __syncthreads();
            sh[tid] += t;
            __syncthreads();
        }
        int inc = sh[tid] + carry_s;
        if (i < N_NODES) {
            rp[i + 1] = inc;
            cursor[i] = inc - v;
            invd[i] = (v > 0) ? (1.0f / (float)v) : 0.0f;
        }
        __syncthreads();
        if (tid == 1023) carry_s = inc;
        __syncthreads();
    }
}

__global__ void k_fill(const int* __restrict__ ei, int* __restrict__ cursor,
                       int* __restrict__ csr) {
    int e = blockIdx.x * blockDim.x + threadIdx.x;
    if (e < N_EDGES) {
        int d = ei[N_EDGES + e];
        int p = atomicAdd(&cursor[d], 1);
        csr[p] = ei[e];
    }
}

// ---------------- weight prep ----------------
// Wc1 [32 k][128 o] fp32 (k<16: W1l, else W1r)
// WT2 [128 o][256 k] bf16 rows = concat(W2l[o][:], W2r[o][:])
// WihT [128 k][768 g] fp32
__global__ void k_prepw(const float* __restrict__ W1l, const float* __restrict__ W1r,
                        const float* __restrict__ W2l, const float* __restrict__ W2r,
                        const float* __restrict__ W_ih,
                        float* __restrict__ Wc1, ushort* __restrict__ WT2,
                        float* __restrict__ WihT) {
    int i = blockIdx.x * blockDim.x + threadIdx.x;
    const int n1 = 32 * 128, n2 = 128 * 256, n3 = 128 * 768;
    if (i < n1) {
        int k = i >> 7, o = i & 127;
        Wc1[i] = (k < 16) ? W1l[o * 16 + k] : W1r[o * 16 + (k - 16)];
    } else if (i < n1 + n2) {
        int j = i - n1; int o = j >> 8, k = j & 255;
        float v = (k < 128) ? W2l[o * 128 + k] : W2r[o * 128 + (k - 128)];
        WT2[j] = f2bf(v);
    } else if (i < n1 + n2 + n3) {
        int j = i - n1 - n2; int k = j / 768, g = j % 768;
        WihT[j] = W_ih[g * 128 + k];
    }
}

// ---------------- SAGE layer 1 (one timestep) -> h1 bf16 ----------------
#define NB1 64
__global__ __launch_bounds__(256) void k_sage1(
        const float* __restrict__ xt, const int* __restrict__ rp,
        const int* __restrict__ csr, const float* __restrict__ invd,
        const float* __restrict__ Wc1, const float* __restrict__ b1l,
        ushort* __restrict__ h1u) {
    __shared__ float u[NB1][32];    // [node][k]  k: 0..15 agg, 16..31 root
    __shared__ float w[32][128];    // k-major weights
    int tid = threadIdx.x;
    int nbase = blockIdx.x * NB1;

    for (int i = tid; i < 32 * 128; i += 256) ((float*)w)[i] = Wc1[i];

    { // phase 1: aggregation, 4 threads per node (float4 per thread)
        int n = tid >> 2, q = tid & 3;
        int node = nbase + n;
        float4 acc = make_float4(0, 0, 0, 0);
        float4 root = make_float4(0, 0, 0, 0);
        if (node < N_NODES) {
            int s = rp[node], e = rp[node + 1];
            for (int i = s; i < e; ++i) {
                int sn = csr[i];
                float4 v = *reinterpret_cast<const float4*>(xt + sn * F_IN + q * 4);
                acc.x += v.x; acc.y += v.y; acc.z += v.z; acc.w += v.w;
            }
            float id = invd[node];
            acc.x *= id; acc.y *= id; acc.z *= id; acc.w *= id;
            root = *reinterpret_cast<const float4*>(xt + node * F_IN + q * 4);
        }
        *reinterpret_cast<float4*>(&u[n][q * 4]) = acc;
        *reinterpret_cast<float4*>(&u[n][16 + q * 4]) = root;
    }
    __syncthreads();

    // phase 2: GEMM [64 x 32] @ [32 x 128]; thread tile 8 nodes x 4 outs
    int og = tid & 31, ng = tid >> 5;
    int o = og * 4;
    float acc[8][4];
#pragma unroll
    for (int j = 0; j < 8; ++j)
#pragma unroll
        for (int c = 0; c < 4; ++c) acc[j][c] = 0.0f;

#pragma unroll
    for (int k = 0; k < 32; k += 4) {
        float4 w0 = *reinterpret_cast<const float4*>(&w[k + 0][o]);
        float4 w1 = *reinterpret_cast<const float4*>(&w[k + 1][o]);
        float4 w2 = *reinterpret_cast<const float4*>(&w[k + 2][o]);
        float4 w3 = *reinterpret_cast<const float4*>(&w[k + 3][o]);
#pragma unroll
        for (int j = 0; j < 8; ++j) {
            float4 uv = *reinterpret_cast<const float4*>(&u[ng * 8 + j][k]);
            acc[j][0] += uv.x * w0.x + uv.y * w1.x + uv.z * w2.x + uv.w * w3.x;
            acc[j][1] += uv.x * w0.y + uv.y * w1.y + uv.z * w2.y + uv.w * w3.y;
            acc[j][2] += uv.x * w0.z + uv.y * w1.z + uv.z * w2.z + uv.w * w3.z;
            acc[j][3] += uv.x * w0.w + uv.y * w1.w + uv.z * w2.w + uv.w * w3.w;
        }
    }

    float4 bv = *reinterpret_cast<const float4*>(b1l + o);
#pragma unroll
    for (int j = 0; j < 8; ++j) {
        int node = nbase + ng * 8 + j;
        if (node < N_NODES) {
            float rx = fmaxf(acc[j][0] + bv.x, 0.0f);
            float ry = fmaxf(acc[j][1] + bv.y, 0.0f);
            float rz = fmaxf(acc[j][2] + bv.z, 0.0f);
            float rw = fmaxf(acc[j][3] + bv.w, 0.0f);
            uint2 pk;
            pk.x = (uint)f2bf(rx) | ((uint)f2bf(ry) << 16);
            pk.y = (uint)f2bf(rz) | ((uint)f2bf(rw) << 16);
            *reinterpret_cast<uint2*>(h1u + (size_t)node * HGd + o) = pk;
        }
    }
}

// ---------------- SAGE layer 2 (bf16 MFMA) + node-mean reduce ----------------
// block: 256 thr (4 waves), 32 nodes. u LDS [32][256] bf16 swizzled. N%32==0.
__global__ __launch_bounds__(256) void k_sage2(
        const ushort* __restrict__ h1u, const int* __restrict__ rp,
        const int* __restrict__ csr, const float* __restrict__ invd,
        const ushort* __restrict__ WT2, const float* __restrict__ b2l,
        float* __restrict__ HgT) {
    __shared__ uint4 usm4[32 * 512 / 16];   // 16 KB
    char* ub = (char*)usm4;
    int tid = threadIdx.x;
    int l = tid & 63, w = tid >> 6;
    int lane15 = l & 15, g4 = l >> 4;
    int nbase = blockIdx.x * 32;

    // B-fragment preload: wave w owns cols [w*32, w*32+32)
    short8 bfr[2][8];
#pragma unroll
    for (int ct = 0; ct < 2; ++ct) {
        int n = w * 32 + ct * 16 + lane15;
        const ushort* bp = WT2 + n * 256 + g4 * 8;
#pragma unroll
        for (int ks = 0; ks < 8; ++ks)
            bfr[ct][ks] = *reinterpret_cast<const short8*>(bp + ks * 32);
    }

    // gather: wave w -> local nodes w*8 .. w*8+7, 4-node interleave for MLP
#pragma unroll
    for (int g = 0; g < 2; ++g) {
        int nl0 = w * 8 + g * 4;
        int s[4], e[4];
#pragma unroll
        for (int q = 0; q < 4; ++q) {
            int node = nbase + nl0 + q;
            s[q] = rp[node]; e[q] = rp[node + 1];
        }
        int m = max(max(e[0] - s[0], e[1] - s[1]), max(e[2] - s[2], e[3] - s[3]));
        float a0[4] = {0, 0, 0, 0}, a1[4] = {0, 0, 0, 0};
        for (int j = 0; j < m; ++j) {
#pragma unroll
            for (int q = 0; q < 4; ++q) {
                if (s[q] + j < e[q]) {
                    int sn = csr[s[q] + j];
                    uint v = *reinterpret_cast<const uint*>(h1u + (size_t)sn * HGd + l * 2);
                    a0[q] += bflo(v); a1[q] += bfhi(v);
                }
            }
        }
#pragma unroll
        for (int q = 0; q < 4; ++q) {
            int nl = nl0 + q, node = nbase + nl;
            float id = invd[node];
            uint agg = (uint)f2bf(a0[q] * id) | ((uint)f2bf(a1[q] * id) << 16);
            uint root = *reinterpret_cast<const uint*>(h1u + (size_t)node * HGd + l * 2);
            int swz = (nl & 7) << 4;
            *reinterpret_cast<uint*>(ub + ((nl * 512 + l * 4) ^ swz)) = agg;
            *reinterpret_cast<uint*>(ub + ((nl * 512 + 256 + l * 4) ^ swz)) = root;
        }
    }
    __syncthreads();

    // MFMA GEMM: [32 nodes x 256 k] @ WT2^T -> [32 x 128], wave w cols w*32..+31
    f32x4 acc[2][2];
#pragma unroll
    for (int rt = 0; rt < 2; ++rt)
#pragma unroll
        for (int ct = 0; ct < 2; ++ct) acc[rt][ct] = (f32x4)(0.0f);

#pragma unroll
    for (int ks = 0; ks < 8; ++ks) {
#pragma unroll
        for (int rt = 0; rt < 2; ++rt) {
            int row = rt * 16 + lane15;
            int byt = (row * 512 + (ks * 32 + g4 * 8) * 2) ^ ((row & 7) << 4);
            short8 af = *reinterpret_cast<const short8*>(ub + byt);
            acc[rt][0] = __builtin_amdgcn_mfma_f32_16x16x32_bf16(af, bfr[0][ks], acc[rt][0], 0, 0, 0);
            acc[rt][1] = __builtin_amdgcn_mfma_f32_16x16x32_bf16(af, bfr[1][ks], acc[rt][1], 0, 0, 0);
        }
    }

    // epilogue: bias + relu + column sums over 32 nodes -> atomic into Hg[t]
#pragma unroll
    for (int ct = 0; ct < 2; ++ct) {
        int n = w * 32 + ct * 16 + lane15;
        float bb = b2l[n];
        float sum = 0.f;
#pragma unroll
        for (int rt = 0; rt < 2; ++rt)
#pragma unroll
            for (int j = 0; j < 4; ++j)
                sum += fmaxf(acc[rt][ct][j] + bb, 0.f);
        sum += __shfl_xor(sum, 16);
        sum += __shfl_xor(sum, 32);
        if (g4 == 0) atomicAdd(&HgT[n], sum);
    }
}

// ---------------- GRU input gates for all timesteps ----------------
__global__ __launch_bounds__(768) void k_gi(const float* __restrict__ Hg,
        const float* __restrict__ WihT, const float* __restrict__ b_ih,
        float* __restrict__ gi_all) {
    __shared__ float x[HGd];
    int t = blockIdx.x, g = threadIdx.x;
    if (g < HGd) x[g] = Hg[t * HGd + g] * INVN;
    __syncthreads();
    float a = b_ih[g];
    for (int k = 0; k < HGd; ++k) a += WihT[k * 768 + g] * x[k];
    gi_all[t * 768 + g] = a;
}

// ---------------- multi-block GRU + head (lock-free grid sync) ----------------
__global__ __launch_bounds__(256) void k_gru_mb(const float* __restrict__ gi_all,
        const float* __restrict__ W_hh, const float* __restrict__ b_hh,
        const float* __restrict__ Wh1, const float* __restrict__ bh1,
        const float* __restrict__ Wh2, const float* __restrict__ bh2,
        float* __restrict__ gh, int* __restrict__ cnt, float* __restrict__ out) {
    int tid = threadIdx.x, b = blockIdx.x;
    int r_loc = tid >> 3, q = tid & 7;
    int row = b * 32 + r_loc;           // 0..767

    // W_hh slice in registers: row, k in [q*32, q*32+32)
    float4 wv[8];
    {
        const float4* wr = reinterpret_cast<const float4*>(W_hh + (size_t)row * HTd + q * 32);
#pragma unroll
        for (int i = 0; i < 8; ++i) wv[i] = wr[i];
    }
    float bh = b_hh[row];

    __shared__ float h[HTd];
    h[tid] = 0.0f;
    __syncthreads();

    for (int t = 0; t < T_STEPS; ++t) {
        float s = 0.f;
#pragma unroll
        for (int i = 0; i < 8; ++i) {
            float4 hv = *reinterpret_cast<const float4*>(&h[q * 32 + i * 4]);
            s += wv[i].x * hv.x + wv[i].y * hv.y + wv[i].z * hv.z + wv[i].w * hv.w;
        }
        s += __shfl_xor(s, 1);
        s += __shfl_xor(s, 2);
        s += __shfl_xor(s, 4);
        if (q == 0)
            __hip_atomic_store(&gh[row], s + bh, __ATOMIC_RELAXED, __HIP_MEMORY_SCOPE_AGENT);
        __threadfence();
        __syncthreads();
        if (tid == 0) {
            __hip_atomic_fetch_add(cnt, 1, __ATOMIC_ACQ_REL, __HIP_MEMORY_SCOPE_AGENT);
            int target = GRU_BLOCKS * (t + 1);
            while (__hip_atomic_load(cnt, __ATOMIC_ACQUIRE, __HIP_MEMORY_SCOPE_AGENT) < target)
                __builtin_amdgcn_s_sleep(2);
        }
        __syncthreads();
        // redundant per-block h update
        float ghr = __hip_atomic_load(&gh[tid],        __ATOMIC_RELAXED, __HIP_MEMORY_SCOPE_AGENT);
        float ghz = __hip_atomic_load(&gh[HTd + tid],  __ATOMIC_RELAXED, __HIP_MEMORY_SCOPE_AGENT);
        float ghn = __hip_atomic_load(&gh[2*HTd + tid],__ATOMIC_RELAXED, __HIP_MEMORY_SCOPE_AGENT);
        float gir = gi_all[t * 768 + tid];
        float giz = gi_all[t * 768 + HTd + tid];
        float gin = gi_all[t * 768 + 2 * HTd + tid];
        float r = 1.0f / (1.0f + expf(-(gir + ghr)));
        float z = 1.0f / (1.0f + expf(-(giz + ghz)));
        float n = tanhf(gin + r * ghn);
        float hn = (1.0f - z) * n + z * h[tid];
        __syncthreads();
        h[tid] = hn;
        __syncthreads();
    }

    if (b == 0) {
        __shared__ float act[64];
        if (tid < 64) {
            float a = bh1[tid];
            const float* wr = Wh1 + tid * HTd;
            for (int k = 0; k < HTd; ++k) a += wr[k] * h[k];
            act[tid] = fmaxf(a, 0.0f);
        }
        __syncthreads();
        if (tid == 0) {
            float y = bh2[0];
            for (int j = 0; j < 64; ++j) y += Wh2[j] * act[j];
            out[0] = y;
        }
    }
}

// ---------------- launch ----------------
extern "C" void kernel_launch(void* const* d_in, const int* in_sizes, int n_in,
                              void* d_out, int out_size, void* d_ws, size_t ws_size,
                              hipStream_t stream) {
    const float* x_seq = (const float*)d_in[0];
    const int*   ei    = (const int*)d_in[1];
    const float* W1l   = (const float*)d_in[2];
    const float* b1l   = (const float*)d_in[3];
    const float* W1r   = (const float*)d_in[4];
    const float* W2l   = (const float*)d_in[5];
    const float* b2l   = (const float*)d_in[6];
    const float* W2r   = (const float*)d_in[7];
    const float* W_ih  = (const float*)d_in[8];
    const float* W_hh  = (const float*)d_in[9];
    const float* b_ih  = (const float*)d_in[10];
    const float* b_hh  = (const float*)d_in[11];
    const float* Wh1   = (const float*)d_in[12];
    const float* bh1   = (const float*)d_in[13];
    const float* Wh2   = (const float*)d_in[14];
    const float* bh2   = (const float*)d_in[15];
    float* out = (float*)d_out;

    char* ws = (char*)d_ws;
    size_t off = 0;
    auto take = [&](size_t nbytes) -> void* {
        void* p = (void*)(ws + off);
        off += (nbytes + 255) & ~(size_t)255;
        return p;
    };
    int*    deg    = (int*)take(N_NODES * 4);
    int*    rp     = (int*)take((N_NODES + 1) * 4);
    int*    cursor = (int*)take(N_NODES * 4);
    int*    csr    = (int*)take(N_EDGES * 4);
    float*  invd   = (float*)take(N_NODES * 4);
    float*  Wc1    = (float*)take(32 * 128 * 4);
    ushort* WT2    = (ushort*)take(128 * 256 * 2);
    float*  WihT   = (float*)take(128 * 768 * 4);
    float*  Hg     = (float*)take(T_STEPS * HGd * 4);
    float*  gi_all = (float*)take(T_STEPS * 768 * 4);
    float*  gh     = (float*)take(768 * 4);
    int*    cnt    = (int*)take(256);
    ushort* h1u    = (ushort*)take((size_t)N_NODES * HGd * 2);

    k_zero<<<(N_NODES + 255) / 256, 256, 0, stream>>>(deg, Hg, cnt);
    k_degree<<<(N_EDGES + 255) / 256, 256, 0, stream>>>(ei, deg);
    k_scan<<<1, 1024, 0, stream>>>(deg, rp, cursor, invd);
    k_fill<<<(N_EDGES + 255) / 256, 256, 0, stream>>>(ei, cursor, csr);
    {
        int total = 32 * 128 + 128 * 256 + 128 * 768;
        k_prepw<<<(total + 255) / 256, 256, 0, stream>>>(W1l, W1r, W2l, W2r, W_ih,
                                                         Wc1, WT2, WihT);
    }
    for (int t = 0; t < T_STEPS; ++t) {
        const float* xt = x_seq + (size_t)t * N_NODES * F_IN;
        k_sage1<<<(N_NODES + NB1 - 1) / NB1, 256, 0, stream>>>(xt, rp, csr, invd, Wc1, b1l, h1u);
        k_sage2<<<N_NODES / 32, 256, 0, stream>>>(h1u, rp, csr, invd, WT2, b2l, Hg + t * HGd);
    }
    k_gi<<<T_STEPS, 768, 0, stream>>>(Hg, WihT, b_ih, gi_all);
    k_gru_mb<<<GRU_BLOCKS, 256, 0, stream>>>(gi_all, W_hh, b_hh, Wh1, bh1, Wh2, bh2,
                                             gh, cnt, out);
}

// Round 3
// 5274.555 us; speedup vs baseline: 2.7752x; 1.4395x over previous
//
#include <hip/hip_runtime.h>
#include <hip/hip_bf16.h>

#define N_NODES 20000
#define N_EDGES 320000
#define T_STEPS 64
#define F_IN    16
#define HGd     128
#define HTd     256
#define INVN    (1.0f/20000.0f)
#define GRU_BLOCKS 24
#define NTILES   625            // 20000/32
#define SAGE2_NT 4              // node-tiles per block
#define SAGE2_NB 157            // ceil(625/4)
#define SAGE1_NB 313            // ceil(20000/64)

typedef __attribute__((ext_vector_type(8))) short short8;
typedef __attribute__((ext_vector_type(4))) float f32x4;

static __device__ __forceinline__ ushort f2bf(float f) {
    __hip_bfloat16 b = __float2bfloat16(f);
    return *reinterpret_cast<ushort*>(&b);
}
static __device__ __forceinline__ float bflo(uint v) { return __uint_as_float(v << 16); }
static __device__ __forceinline__ float bfhi(uint v) { return __uint_as_float(v & 0xffff0000u); }

// ---------------- init ----------------
__global__ void k_zero(int* __restrict__ deg, float* __restrict__ HgP, int* __restrict__ cnt) {
    int i = blockIdx.x * blockDim.x + threadIdx.x;
    if (i < N_NODES) deg[i] = 0;
    if (i < T_STEPS * 8 * HGd) HgP[i] = 0.0f;
    if (i == 0) *cnt = 0;
}

__global__ void k_degree(const int* __restrict__ ei, int* __restrict__ deg) {
    int e = blockIdx.x * blockDim.x + threadIdx.x;
    if (e < N_EDGES) atomicAdd(&deg[ei[N_EDGES + e]], 1);
}

__global__ __launch_bounds__(1024) void k_scan(const int* __restrict__ deg,
        int* __restrict__ rp, int* __restrict__ cursor, float* __restrict__ invd) {
    __shared__ int sh[1024];
    __shared__ int carry_s;
    int tid = threadIdx.x;
    if (tid == 0) { carry_s = 0; rp[0] = 0; }
    __syncthreads();
    for (int base = 0; base < N_NODES; base += 1024) {
        int i = base + tid;
        int v = (i < N_NODES) ? deg[i] : 0;
        sh[tid] = v;
        __syncthreads();
        for (int off = 1; off < 1024; off <<= 1) {
            int t = (tid >= off) ? sh[tid - off] : 0;
            __syncthreads();
            sh[tid] += t;
            __syncthreads();
        }
        int inc = sh[tid] + carry_s;
        if (i < N_NODES) {
            rp[i + 1] = inc;
            cursor[i] = inc - v;
            invd[i] = (v > 0) ? (1.0f / (float)v) : 0.0f;
        }
        __syncthreads();
        if (tid == 1023) carry_s = inc;
        __syncthreads();
    }
}

__global__ void k_fill(const int* __restrict__ ei, int* __restrict__ cursor,
                       int* __restrict__ csr) {
    int e = blockIdx.x * blockDim.x + threadIdx.x;
    if (e < N_EDGES) {
        int d = ei[N_EDGES + e];
        int p = atomicAdd(&cursor[d], 1);
        csr[p] = ei[e];
    }
}

// ---------------- weight prep ----------------
__global__ void k_prepw(const float* __restrict__ W1l, const float* __restrict__ W1r,
                        const float* __restrict__ W2l, const float* __restrict__ W2r,
                        const float* __restrict__ W_ih,
                        float* __restrict__ Wc1, ushort* __restrict__ WT2,
                        float* __restrict__ WihT) {
    int i = blockIdx.x * blockDim.x + threadIdx.x;
    const int n1 = 32 * 128, n2 = 128 * 256, n3 = 128 * 768;
    if (i < n1) {
        int k = i >> 7, o = i & 127;
        Wc1[i] = (k < 16) ? W1l[o * 16 + k] : W1r[o * 16 + (k - 16)];
    } else if (i < n1 + n2) {
        int j = i - n1; int o = j >> 8, k = j & 255;
        float v = (k < 128) ? W2l[o * 128 + k] : W2r[o * 128 + (k - 128)];
        WT2[j] = f2bf(v);
    } else if (i < n1 + n2 + n3) {
        int j = i - n1 - n2; int k = j / 768, g = j % 768;
        WihT[j] = W_ih[g * 128 + k];
    }
}

// ---------------- SAGE layer 1, batched over C timesteps ----------------
#define NB1 64
__global__ __launch_bounds__(256) void k_sage1(
        const float* __restrict__ x_seq, const int* __restrict__ rp,
        const int* __restrict__ csr, const float* __restrict__ invd,
        const float* __restrict__ Wc1, const float* __restrict__ b1l,
        ushort* __restrict__ h1u, int t0, int C) {
    __shared__ float u[NB1][32];
    __shared__ float w[32][128];
    int tid = threadIdx.x;
    int b = blockIdx.x;
    int tl = b % C, nb = b / C;           // tl rides the XCD round-robin
    const float* xt = x_seq + (size_t)(t0 + tl) * N_NODES * F_IN;
    ushort* h1 = h1u + (size_t)tl * N_NODES * HGd;
    int nbase = nb * NB1;

    for (int i = tid; i < 32 * 128; i += 256) ((float*)w)[i] = Wc1[i];

    { // aggregation: 4 threads per node (float4 per thread)
        int n = tid >> 2, q = tid & 3;
        int node = nbase + n;
        float4 acc = make_float4(0, 0, 0, 0);
        float4 root = make_float4(0, 0, 0, 0);
        if (node < N_NODES) {
            int s = rp[node], e = rp[node + 1];
            for (int i = s; i < e; ++i) {
                int sn = csr[i];
                float4 v = *reinterpret_cast<const float4*>(xt + sn * F_IN + q * 4);
                acc.x += v.x; acc.y += v.y; acc.z += v.z; acc.w += v.w;
            }
            float id = invd[node];
            acc.x *= id; acc.y *= id; acc.z *= id; acc.w *= id;
            root = *reinterpret_cast<const float4*>(xt + node * F_IN + q * 4);
        }
        *reinterpret_cast<float4*>(&u[n][q * 4]) = acc;
        *reinterpret_cast<float4*>(&u[n][16 + q * 4]) = root;
    }
    __syncthreads();

    // GEMM [64 x 32] @ [32 x 128]; thread tile 8 nodes x 4 outs
    int og = tid & 31, ng = tid >> 5;
    int o = og * 4;
    float acc[8][4];
#pragma unroll
    for (int j = 0; j < 8; ++j)
#pragma unroll
        for (int c = 0; c < 4; ++c) acc[j][c] = 0.0f;

#pragma unroll
    for (int k = 0; k < 32; k += 4) {
        float4 w0 = *reinterpret_cast<const float4*>(&w[k + 0][o]);
        float4 w1 = *reinterpret_cast<const float4*>(&w[k + 1][o]);
        float4 w2 = *reinterpret_cast<const float4*>(&w[k + 2][o]);
        float4 w3 = *reinterpret_cast<const float4*>(&w[k + 3][o]);
#pragma unroll
        for (int j = 0; j < 8; ++j) {
            float4 uv = *reinterpret_cast<const float4*>(&u[ng * 8 + j][k]);
            acc[j][0] += uv.x * w0.x + uv.y * w1.x + uv.z * w2.x + uv.w * w3.x;
            acc[j][1] += uv.x * w0.y + uv.y * w1.y + uv.z * w2.y + uv.w * w3.y;
            acc[j][2] += uv.x * w0.z + uv.y * w1.z + uv.z * w2.z + uv.w * w3.z;
            acc[j][3] += uv.x * w0.w + uv.y * w1.w + uv.z * w2.w + uv.w * w3.w;
        }
    }

    float4 bv = *reinterpret_cast<const float4*>(b1l + o);
#pragma unroll
    for (int j = 0; j < 8; ++j) {
        int node = nbase + ng * 8 + j;
        if (node < N_NODES) {
            float rx = fmaxf(acc[j][0] + bv.x, 0.0f);
            float ry = fmaxf(acc[j][1] + bv.y, 0.0f);
            float rz = fmaxf(acc[j][2] + bv.z, 0.0f);
            float rw = fmaxf(acc[j][3] + bv.w, 0.0f);
            uint2 pk;
            pk.x = (uint)f2bf(rx) | ((uint)f2bf(ry) << 16);
            pk.y = (uint)f2bf(rz) | ((uint)f2bf(rw) << 16);
            *reinterpret_cast<uint2*>(h1 + (size_t)node * HGd + o) = pk;
        }
    }
}

// ---------------- SAGE layer 2 (bf16 MFMA), batched, 4 node-tiles/block ----------------
__global__ __launch_bounds__(256) void k_sage2(
        const ushort* __restrict__ h1u, const int* __restrict__ rp,
        const int* __restrict__ csr, const float* __restrict__ invd,
        const ushort* __restrict__ WT2, const float* __restrict__ b2l,
        float* __restrict__ HgP, int t0, int C) {
    __shared__ uint4 usm4[32 * 512 / 16];   // 16 KB
    char* ub = (char*)usm4;
    int tid = threadIdx.x;
    int l = tid & 63, w = tid >> 6;
    int lane15 = l & 15, g4 = l >> 4;
    int b = blockIdx.x;
    int tl = b % C, nbq = b / C;            // nbq in 0..156
    int t = t0 + tl;
    const ushort* h1 = h1u + (size_t)tl * N_NODES * HGd;

    // B-fragment preload: wave w owns cols [w*32, w*32+32)
    short8 bfr[2][8];
#pragma unroll
    for (int ct = 0; ct < 2; ++ct) {
        int n = w * 32 + ct * 16 + lane15;
        const ushort* bp = WT2 + n * 256 + g4 * 8;
#pragma unroll
        for (int ks = 0; ks < 8; ++ks)
            bfr[ct][ks] = *reinterpret_cast<const short8*>(bp + ks * 32);
    }
    float bb[2];
#pragma unroll
    for (int ct = 0; ct < 2; ++ct) bb[ct] = b2l[w * 32 + ct * 16 + lane15];

    float suma[2] = {0.f, 0.f};

    for (int it = 0; it < SAGE2_NT; ++it) {
        int ntile = nbq * SAGE2_NT + it;
        if (ntile >= NTILES) break;         // uniform across block
        int nbase = ntile * 32;

        // gather: wave w -> local nodes w*8..w*8+7, 4-node interleave
#pragma unroll
        for (int g = 0; g < 2; ++g) {
            int nl0 = w * 8 + g * 4;
            int s[4], e[4];
#pragma unroll
            for (int q = 0; q < 4; ++q) {
                int node = nbase + nl0 + q;
                s[q] = rp[node]; e[q] = rp[node + 1];
            }
            int m = max(max(e[0] - s[0], e[1] - s[1]), max(e[2] - s[2], e[3] - s[3]));
            float a0[4] = {0, 0, 0, 0}, a1[4] = {0, 0, 0, 0};
            for (int j = 0; j < m; ++j) {
#pragma unroll
                for (int q = 0; q < 4; ++q) {
                    if (s[q] + j < e[q]) {
                        int sn = csr[s[q] + j];
                        uint v = *reinterpret_cast<const uint*>(h1 + (size_t)sn * HGd + l * 2);
                        a0[q] += bflo(v); a1[q] += bfhi(v);
                    }
                }
            }
#pragma unroll
            for (int q = 0; q < 4; ++q) {
                int nl = nl0 + q, node = nbase + nl;
                float id = invd[node];
                uint agg = (uint)f2bf(a0[q] * id) | ((uint)f2bf(a1[q] * id) << 16);
                uint root = *reinterpret_cast<const uint*>(h1 + (size_t)node * HGd + l * 2);
                int swz = (nl & 7) << 4;
                *reinterpret_cast<uint*>(ub + ((nl * 512 + l * 4) ^ swz)) = agg;
                *reinterpret_cast<uint*>(ub + ((nl * 512 + 256 + l * 4) ^ swz)) = root;
            }
        }
        __syncthreads();

        // MFMA: [32 x 256] @ WT2^T -> [32 x 128]; wave w cols w*32..+31
        f32x4 acc[2][2];
#pragma unroll
        for (int rt = 0; rt < 2; ++rt)
#pragma unroll
            for (int ct = 0; ct < 2; ++ct) acc[rt][ct] = (f32x4)(0.0f);

#pragma unroll
        for (int ks = 0; ks < 8; ++ks) {
#pragma unroll
            for (int rt = 0; rt < 2; ++rt) {
                int row = rt * 16 + lane15;
                int byt = (row * 512 + (ks * 32 + g4 * 8) * 2) ^ ((row & 7) << 4);
                short8 af = *reinterpret_cast<const short8*>(ub + byt);
                acc[rt][0] = __builtin_amdgcn_mfma_f32_16x16x32_bf16(af, bfr[0][ks], acc[rt][0], 0, 0, 0);
                acc[rt][1] = __builtin_amdgcn_mfma_f32_16x16x32_bf16(af, bfr[1][ks], acc[rt][1], 0, 0, 0);
            }
        }

        // bias + relu + accumulate per-column partial sums over 32 nodes
#pragma unroll
        for (int ct = 0; ct < 2; ++ct) {
#pragma unroll
            for (int rt = 0; rt < 2; ++rt)
#pragma unroll
                for (int j = 0; j < 4; ++j)
                    suma[ct] += fmaxf(acc[rt][ct][j] + bb[ct], 0.f);
        }
        __syncthreads();   // protect u before next tile's gather writes
    }

    // cross-lane reduce + one atomic per output element, spread over 8 partials
#pragma unroll
    for (int ct = 0; ct < 2; ++ct) {
        float sum = suma[ct];
        sum += __shfl_xor(sum, 16);
        sum += __shfl_xor(sum, 32);
        if (g4 == 0) {
            int n = w * 32 + ct * 16 + lane15;
            atomicAdd(&HgP[(t * 8 + (nbq & 7)) * HGd + n], sum);
        }
    }
}

// ---------------- GRU input gates (folds 8-way Hg partials) ----------------
__global__ __launch_bounds__(768) void k_gi(const float* __restrict__ HgP,
        const float* __restrict__ WihT, const float* __restrict__ b_ih,
        float* __restrict__ gi_all) {
    __shared__ float x[HGd];
    int t = blockIdx.x, g = threadIdx.x;
    if (g < HGd) {
        float s = 0.f;
#pragma unroll
        for (int p = 0; p < 8; ++p) s += HgP[(t * 8 + p) * HGd + g];
        x[g] = s * INVN;
    }
    __syncthreads();
    float a = b_ih[g];
    for (int k = 0; k < HGd; ++k) a += WihT[k * 768 + g] * x[k];
    gi_all[t * 768 + g] = a;
}

// ---------------- multi-block GRU + head (lock-free grid sync) ----------------
__global__ __launch_bounds__(256) void k_gru_mb(const float* __restrict__ gi_all,
        const float* __restrict__ W_hh, const float* __restrict__ b_hh,
        const float* __restrict__ Wh1, const float* __restrict__ bh1,
        const float* __restrict__ Wh2, const float* __restrict__ bh2,
        float* __restrict__ gh, int* __restrict__ cnt, float* __restrict__ out) {
    int tid = threadIdx.x, b = blockIdx.x;
    int r_loc = tid >> 3, q = tid & 7;
    int row = b * 32 + r_loc;

    float4 wv[8];
    {
        const float4* wr = reinterpret_cast<const float4*>(W_hh + (size_t)row * HTd + q * 32);
#pragma unroll
        for (int i = 0; i < 8; ++i) wv[i] = wr[i];
    }
    float bh = b_hh[row];

    __shared__ float h[HTd];
    h[tid] = 0.0f;
    __syncthreads();

    for (int t = 0; t < T_STEPS; ++t) {
        float s = 0.f;
#pragma unroll
        for (int i = 0; i < 8; ++i) {
            float4 hv = *reinterpret_cast<const float4*>(&h[q * 32 + i * 4]);
            s += wv[i].x * hv.x + wv[i].y * hv.y + wv[i].z * hv.z + wv[i].w * hv.w;
        }
        s += __shfl_xor(s, 1);
        s += __shfl_xor(s, 2);
        s += __shfl_xor(s, 4);
        if (q == 0)
            __hip_atomic_store(&gh[row], s + bh, __ATOMIC_RELAXED, __HIP_MEMORY_SCOPE_AGENT);
        __threadfence();
        __syncthreads();
        if (tid == 0) {
            __hip_atomic_fetch_add(cnt, 1, __ATOMIC_ACQ_REL, __HIP_MEMORY_SCOPE_AGENT);
            int target = GRU_BLOCKS * (t + 1);
            while (__hip_atomic_load(cnt, __ATOMIC_ACQUIRE, __HIP_MEMORY_SCOPE_AGENT) < target)
                __builtin_amdgcn_s_sleep(2);
        }
        __syncthreads();
        float ghr = __hip_atomic_load(&gh[tid],        __ATOMIC_RELAXED, __HIP_MEMORY_SCOPE_AGENT);
        float ghz = __hip_atomic_load(&gh[HTd + tid],  __ATOMIC_RELAXED, __HIP_MEMORY_SCOPE_AGENT);
        float ghn = __hip_atomic_load(&gh[2*HTd + tid],__ATOMIC_RELAXED, __HIP_MEMORY_SCOPE_AGENT);
        float gir = gi_all[t * 768 + tid];
        float giz = gi_all[t * 768 + HTd + tid];
        float gin = gi_all[t * 768 + 2 * HTd + tid];
        float r = 1.0f / (1.0f + expf(-(gir + ghr)));
        float z = 1.0f / (1.0f + expf(-(giz + ghz)));
        float n = tanhf(gin + r * ghn);
        float hn = (1.0f - z) * n + z * h[tid];
        __syncthreads();
        h[tid] = hn;
        __syncthreads();
    }

    if (b == 0) {
        __shared__ float act[64];
        if (tid < 64) {
            float a = bh1[tid];
            const float* wr = Wh1 + tid * HTd;
            for (int k = 0; k < HTd; ++k) a += wr[k] * h[k];
            act[tid] = fmaxf(a, 0.0f);
        }
        __syncthreads();
        if (tid == 0) {
            float y = bh2[0];
            for (int j = 0; j < 64; ++j) y += Wh2[j] * act[j];
            out[0] = y;
        }
    }
}

// ---------------- launch ----------------
extern "C" void kernel_launch(void* const* d_in, const int* in_sizes, int n_in,
                              void* d_out, int out_size, void* d_ws, size_t ws_size,
                              hipStream_t stream) {
    const float* x_seq = (const float*)d_in[0];
    const int*   ei    = (const int*)d_in[1];
    const float* W1l   = (const float*)d_in[2];
    const float* b1l   = (const float*)d_in[3];
    const float* W1r   = (const float*)d_in[4];
    const float* W2l   = (const float*)d_in[5];
    const float* b2l   = (const float*)d_in[6];
    const float* W2r   = (const float*)d_in[7];
    const float* W_ih  = (const float*)d_in[8];
    const float* W_hh  = (const float*)d_in[9];
    const float* b_ih  = (const float*)d_in[10];
    const float* b_hh  = (const float*)d_in[11];
    const float* Wh1   = (const float*)d_in[12];
    const float* bh1   = (const float*)d_in[13];
    const float* Wh2   = (const float*)d_in[14];
    const float* bh2   = (const float*)d_in[15];
    float* out = (float*)d_out;

    char* ws = (char*)d_ws;
    size_t off = 0;
    auto take = [&](size_t nbytes) -> void* {
        void* p = (void*)(ws + off);
        off += (nbytes + 255) & ~(size_t)255;
        return p;
    };
    int*    deg    = (int*)take(N_NODES * 4);
    int*    rp     = (int*)take((N_NODES + 1) * 4);
    int*    cursor = (int*)take(N_NODES * 4);
    int*    csr    = (int*)take(N_EDGES * 4);
    float*  invd   = (float*)take(N_NODES * 4);
    float*  Wc1    = (float*)take(32 * 128 * 4);
    ushort* WT2    = (ushort*)take(128 * 256 * 2);
    float*  WihT   = (float*)take(128 * 768 * 4);
    float*  HgP    = (float*)take(T_STEPS * 8 * HGd * 4);
    float*  gi_all = (float*)take(T_STEPS * 768 * 4);
    float*  gh     = (float*)take(768 * 4);
    int*    cnt    = (int*)take(256);

    const size_t slice = (size_t)N_NODES * HGd * 2;   // one timestep of h1 (bf16)
    int T_CH = 8;
    while (T_CH > 1 && off + (size_t)T_CH * ((slice + 255) & ~(size_t)255) > ws_size)
        T_CH >>= 1;
    ushort* h1u = (ushort*)take((size_t)T_CH * ((slice + 255) & ~(size_t)255));

    k_zero<<<256, 256, 0, stream>>>(deg, HgP, cnt);
    k_degree<<<(N_EDGES + 255) / 256, 256, 0, stream>>>(ei, deg);
    k_scan<<<1, 1024, 0, stream>>>(deg, rp, cursor, invd);
    k_fill<<<(N_EDGES + 255) / 256, 256, 0, stream>>>(ei, cursor, csr);
    {
        int total = 32 * 128 + 128 * 256 + 128 * 768;
        k_prepw<<<(total + 255) / 256, 256, 0, stream>>>(W1l, W1r, W2l, W2r, W_ih,
                                                         Wc1, WT2, WihT);
    }
    for (int t0 = 0; t0 < T_STEPS; t0 += T_CH) {
        int C = T_CH;
        k_sage1<<<C * SAGE1_NB, 256, 0, stream>>>(x_seq, rp, csr, invd, Wc1, b1l, h1u, t0, C);
        k_sage2<<<C * SAGE2_NB, 256, 0, stream>>>(h1u, rp, csr, invd, WT2, b2l, HgP, t0, C);
    }
    k_gi<<<T_STEPS, 768, 0, stream>>>(HgP, WihT, b_ih, gi_all);
    k_gru_mb<<<GRU_BLOCKS, 256, 0, stream>>>(gi_all, W_hh, b_hh, Wh1, bh1, Wh2, bh2,
                                             gh, cnt, out);
}

// Round 4
// 2982.386 us; speedup vs baseline: 4.9082x; 1.7686x over previous
//
#include <hip/hip_runtime.h>
#include <hip/hip_bf16.h>

#define N_NODES 20000
#define N_EDGES 320000
#define T_STEPS 64
#define F_IN    16
#define HGd     128
#define HTd     256
#define INVN    (1.0f/20000.0f)
#define GRU_BLOCKS 12
#define NTILES   625            // 20000/32  (sage2 tiles)
#define S1_TILES 313            // ceil(20000/64)

typedef __attribute__((ext_vector_type(8))) short short8;
typedef __attribute__((ext_vector_type(4))) float f32x4;

static __device__ __forceinline__ ushort f2bf(float f) {
    __hip_bfloat16 b = __float2bfloat16(f);
    return *reinterpret_cast<ushort*>(&b);
}
static __device__ __forceinline__ float bflo(uint v) { return __uint_as_float(v << 16); }
static __device__ __forceinline__ float bfhi(uint v) { return __uint_as_float(v & 0xffff0000u); }

// ---------------- init ----------------
__global__ void k_zero(int* __restrict__ deg, float* __restrict__ HgP,
                       int* __restrict__ cnt, int* __restrict__ jobc,
                       int* __restrict__ bins) {
    int i = blockIdx.x * blockDim.x + threadIdx.x;
    if (i < N_NODES) deg[i] = 0;
    if (i < T_STEPS * 8 * HGd) HgP[i] = 0.0f;
    if (i == 0) *cnt = 0;
    if (i < 32) jobc[i] = 0;
    if (i < 256) bins[i] = 0;
}

__global__ void k_degree(const int* __restrict__ ei, int* __restrict__ deg) {
    int e = blockIdx.x * blockDim.x + threadIdx.x;
    if (e < N_EDGES) atomicAdd(&deg[ei[N_EDGES + e]], 1);
}

__global__ __launch_bounds__(1024) void k_scan(const int* __restrict__ deg,
        int* __restrict__ rp, int* __restrict__ cursor, float* __restrict__ invd) {
    __shared__ int sh[1024];
    __shared__ int carry_s;
    int tid = threadIdx.x;
    if (tid == 0) { carry_s = 0; rp[0] = 0; }
    __syncthreads();
    for (int base = 0; base < N_NODES; base += 1024) {
        int i = base + tid;
        int v = (i < N_NODES) ? deg[i] : 0;
        sh[tid] = v;
        __syncthreads();
        for (int off = 1; off < 1024; off <<= 1) {
            int t = (tid >= off) ? sh[tid - off] : 0;
            __syncthreads();
            sh[tid] += t;
            __syncthreads();
        }
        int inc = sh[tid] + carry_s;
        if (i < N_NODES) {
            rp[i + 1] = inc;
            cursor[i] = inc - v;
            invd[i] = (v > 0) ? (1.0f / (float)v) : 0.0f;
        }
        __syncthreads();
        if (tid == 1023) carry_s = inc;
        __syncthreads();
    }
}

__global__ void k_fill(const int* __restrict__ ei, int* __restrict__ cursor,
                       int* __restrict__ csr) {
    int e = blockIdx.x * blockDim.x + threadIdx.x;
    if (e < N_EDGES) {
        int d = ei[N_EDGES + e];
        int p = atomicAdd(&cursor[d], 1);
        csr[p] = ei[e];
    }
}

// ---------------- degree-sort permutation (counting sort) ----------------
__global__ void k_hist(const int* __restrict__ deg, int* __restrict__ bins) {
    int i = blockIdx.x * blockDim.x + threadIdx.x;
    if (i < N_NODES) atomicAdd(&bins[min(deg[i], 255)], 1);
}

__global__ __launch_bounds__(256) void k_binscan(const int* __restrict__ bins,
                                                 int* __restrict__ bincur) {
    __shared__ int sh[256];
    int tid = threadIdx.x;
    sh[tid] = bins[tid];
    __syncthreads();
    for (int off = 1; off < 256; off <<= 1) {
        int v = (tid >= off) ? sh[tid - off] : 0;
        __syncthreads();
        sh[tid] += v;
        __syncthreads();
    }
    bincur[tid] = sh[tid] - bins[tid];   // exclusive prefix
}

__global__ void k_perm(const int* __restrict__ deg, int* __restrict__ bincur,
                       int* __restrict__ perm) {
    int i = blockIdx.x * blockDim.x + threadIdx.x;
    if (i < N_NODES) {
        int d = min(deg[i], 255);
        int p = atomicAdd(&bincur[d], 1);
        perm[p] = i;
    }
}

// ---------------- weight prep ----------------
__global__ void k_prepw(const float* __restrict__ W1l, const float* __restrict__ W1r,
                        const float* __restrict__ W2l, const float* __restrict__ W2r,
                        const float* __restrict__ W_ih,
                        float* __restrict__ Wc1, ushort* __restrict__ WT2,
                        float* __restrict__ WihT) {
    int i = blockIdx.x * blockDim.x + threadIdx.x;
    const int n1 = 32 * 128, n2 = 128 * 256, n3 = 128 * 768;
    if (i < n1) {
        int k = i >> 7, o = i & 127;
        Wc1[i] = (k < 16) ? W1l[o * 16 + k] : W1r[o * 16 + (k - 16)];
    } else if (i < n1 + n2) {
        int j = i - n1; int o = j >> 8, k = j & 255;
        float v = (k < 128) ? W2l[o * 128 + k] : W2r[o * 128 + (k - 128)];
        WT2[j] = f2bf(v);
    } else if (i < n1 + n2 + n3) {
        int j = i - n1 - n2; int k = j / 768, g = j % 768;
        WihT[j] = W_ih[g * 128 + k];
    }
}

// ---------------- SAGE layer 1 (work-stealing, degree-sorted) ----------------
__global__ __launch_bounds__(256) void k_sage1(
        const float* __restrict__ x_seq, const int* __restrict__ rp,
        const int* __restrict__ csr, const float* __restrict__ invd,
        const float* __restrict__ Wc1, const float* __restrict__ b1l,
        const int* __restrict__ perm, ushort* __restrict__ h1u,
        int* __restrict__ jobc, int t0, int C) {
    __shared__ float u[64][32];
    __shared__ float w[32][128];
    __shared__ int pnode[64];
    __shared__ int job_s;
    int tid = threadIdx.x;

    for (int i = tid; i < 32 * 128; i += 256) ((float*)w)[i] = Wc1[i];

    const int njobs = C * S1_TILES;
    for (;;) {
        if (tid == 0) job_s = atomicAdd(jobc, 1);
        __syncthreads();                 // job ready; prior GEMM reads of u done
        int job = job_s;
        if (job >= njobs) break;
        int tl = job / S1_TILES, nb = job % S1_TILES;
        const float* xt = x_seq + (size_t)(t0 + tl) * N_NODES * F_IN;
        ushort* h1 = h1u + (size_t)tl * N_NODES * HGd;
        int nbase = nb * 64;
        if (tid < 64) pnode[tid] = (nbase + tid < N_NODES) ? perm[nbase + tid] : -1;
        __syncthreads();

        { // aggregation: 4 threads per node (float4 per thread)
            int n = tid >> 2, q = tid & 3;
            int node = pnode[n];
            float4 acc = make_float4(0, 0, 0, 0);
            float4 root = make_float4(0, 0, 0, 0);
            if (node >= 0) {
                int s = rp[node], e = rp[node + 1];
                for (int i = s; i < e; ++i) {
                    int sn = csr[i];
                    float4 v = *reinterpret_cast<const float4*>(xt + sn * F_IN + q * 4);
                    acc.x += v.x; acc.y += v.y; acc.z += v.z; acc.w += v.w;
                }
                float id = invd[node];
                acc.x *= id; acc.y *= id; acc.z *= id; acc.w *= id;
                root = *reinterpret_cast<const float4*>(xt + node * F_IN + q * 4);
            }
            *reinterpret_cast<float4*>(&u[n][q * 4]) = acc;
            *reinterpret_cast<float4*>(&u[n][16 + q * 4]) = root;
        }
        __syncthreads();

        // GEMM [64 x 32] @ [32 x 128]; thread tile 8 nodes x 4 outs
        int og = tid & 31, ng = tid >> 5;
        int o = og * 4;
        float acc[8][4];
#pragma unroll
        for (int j = 0; j < 8; ++j)
#pragma unroll
            for (int c = 0; c < 4; ++c) acc[j][c] = 0.0f;

#pragma unroll
        for (int k = 0; k < 32; k += 4) {
            float4 w0 = *reinterpret_cast<const float4*>(&w[k + 0][o]);
            float4 w1 = *reinterpret_cast<const float4*>(&w[k + 1][o]);
            float4 w2 = *reinterpret_cast<const float4*>(&w[k + 2][o]);
            float4 w3 = *reinterpret_cast<const float4*>(&w[k + 3][o]);
#pragma unroll
            for (int j = 0; j < 8; ++j) {
                float4 uv = *reinterpret_cast<const float4*>(&u[ng * 8 + j][k]);
                acc[j][0] += uv.x * w0.x + uv.y * w1.x + uv.z * w2.x + uv.w * w3.x;
                acc[j][1] += uv.x * w0.y + uv.y * w1.y + uv.z * w2.y + uv.w * w3.y;
                acc[j][2] += uv.x * w0.z + uv.y * w1.z + uv.z * w2.z + uv.w * w3.z;
                acc[j][3] += uv.x * w0.w + uv.y * w1.w + uv.z * w2.w + uv.w * w3.w;
            }
        }

        float4 bv = *reinterpret_cast<const float4*>(b1l + o);
#pragma unroll
        for (int j = 0; j < 8; ++j) {
            int node = pnode[ng * 8 + j];
            if (node >= 0) {
                float rx = fmaxf(acc[j][0] + bv.x, 0.0f);
                float ry = fmaxf(acc[j][1] + bv.y, 0.0f);
                float rz = fmaxf(acc[j][2] + bv.z, 0.0f);
                float rw = fmaxf(acc[j][3] + bv.w, 0.0f);
                uint2 pk;
                pk.x = (uint)f2bf(rx) | ((uint)f2bf(ry) << 16);
                pk.y = (uint)f2bf(rz) | ((uint)f2bf(rw) << 16);
                *reinterpret_cast<uint2*>(h1 + (size_t)node * HGd + o) = pk;
            }
        }
    }
}

// ---------------- SAGE layer 2 (bf16 MFMA, vectorized gather, work-stealing) ----------------
__global__ __launch_bounds__(256) void k_sage2(
        const ushort* __restrict__ h1u, const int* __restrict__ rp,
        const int* __restrict__ csr, const float* __restrict__ invd,
        const ushort* __restrict__ WT2, const float* __restrict__ b2l,
        const int* __restrict__ perm, float* __restrict__ HgP,
        int* __restrict__ jobc, int t0, int C) {
    __shared__ uint4 usm4[32 * 512 / 16];   // 16 KB
    __shared__ int pnode[32];
    __shared__ int job_s;
    char* ub = (char*)usm4;
    int tid = threadIdx.x;
    int l = tid & 63, w = tid >> 6;
    int lane15 = l & 15, g4 = l >> 4;

    // B-fragment preload: wave w owns cols [w*32, w*32+32)
    short8 bfr[2][8];
    float bb[2];
#pragma unroll
    for (int ct = 0; ct < 2; ++ct) {
        int n = w * 32 + ct * 16 + lane15;
        const ushort* bp = WT2 + n * 256 + g4 * 8;
#pragma unroll
        for (int ks = 0; ks < 8; ++ks)
            bfr[ct][ks] = *reinterpret_cast<const short8*>(bp + ks * 32);
        bb[ct] = b2l[n];
    }

    const int njobs = C * NTILES;
    for (;;) {
        if (tid == 0) job_s = atomicAdd(jobc, 1);
        __syncthreads();                 // job ready; prior MFMA LDS reads done
        int job = job_s;
        if (job >= njobs) break;
        int tl = job / NTILES, ntile = job % NTILES;
        int t = t0 + tl;
        int nbase = ntile * 32;
        const ushort* h1 = h1u + (size_t)tl * N_NODES * HGd;
        if (tid < 32) pnode[tid] = perm[nbase + tid];
        __syncthreads();

        // root rows: block-cooperative copy, 512 x 16B
        for (int i = tid; i < 512; i += 256) {
            int nl = i >> 4, seg = i & 15;
            uint4 v = *reinterpret_cast<const uint4*>(h1 + (size_t)pnode[nl] * HGd + seg * 8);
            *reinterpret_cast<uint4*>(ub + ((nl * 512 + 256 + seg * 16) ^ ((nl & 7) << 4))) = v;
        }

        // gather: wave w -> 8 nodes in 2 passes of 4; 16 lanes per node row
#pragma unroll
        for (int g = 0; g < 2; ++g) {
            int nl = w * 8 + g * 4 + g4;
            int node = pnode[nl];
            int s = rp[node], e = rp[node + 1];
            float af[8] = {0, 0, 0, 0, 0, 0, 0, 0};
            for (int j = s; j < e; ++j) {
                int sn = csr[j];
                uint4 v = *reinterpret_cast<const uint4*>(h1 + (size_t)sn * HGd + lane15 * 8);
                af[0] += bflo(v.x); af[1] += bfhi(v.x);
                af[2] += bflo(v.y); af[3] += bfhi(v.y);
                af[4] += bflo(v.z); af[5] += bfhi(v.z);
                af[6] += bflo(v.w); af[7] += bfhi(v.w);
            }
            float id = invd[node];
            uint4 pk;
            pk.x = (uint)f2bf(af[0] * id) | ((uint)f2bf(af[1] * id) << 16);
            pk.y = (uint)f2bf(af[2] * id) | ((uint)f2bf(af[3] * id) << 16);
            pk.z = (uint)f2bf(af[4] * id) | ((uint)f2bf(af[5] * id) << 16);
            pk.w = (uint)f2bf(af[6] * id) | ((uint)f2bf(af[7] * id) << 16);
            *reinterpret_cast<uint4*>(ub + ((nl * 512 + lane15 * 16) ^ ((nl & 7) << 4))) = pk;
        }
        __syncthreads();

        // MFMA: [32 x 256] @ WT2^T -> [32 x 128]; wave w cols w*32..+31
        f32x4 acc[2][2];
#pragma unroll
        for (int rt = 0; rt < 2; ++rt)
#pragma unroll
            for (int ct = 0; ct < 2; ++ct) acc[rt][ct] = (f32x4)(0.0f);

#pragma unroll
        for (int ks = 0; ks < 8; ++ks) {
#pragma unroll
            for (int rt = 0; rt < 2; ++rt) {
                int row = rt * 16 + lane15;
                int byt = (row * 512 + (ks * 32 + g4 * 8) * 2) ^ ((row & 7) << 4);
                short8 af = *reinterpret_cast<const short8*>(ub + byt);
                acc[rt][0] = __builtin_amdgcn_mfma_f32_16x16x32_bf16(af, bfr[0][ks], acc[rt][0], 0, 0, 0);
                acc[rt][1] = __builtin_amdgcn_mfma_f32_16x16x32_bf16(af, bfr[1][ks], acc[rt][1], 0, 0, 0);
            }
        }

        // bias + relu + column sums over 32 nodes -> atomic flush per tile
#pragma unroll
        for (int ct = 0; ct < 2; ++ct) {
            float sum = 0.f;
#pragma unroll
            for (int rt = 0; rt < 2; ++rt)
#pragma unroll
                for (int j = 0; j < 4; ++j)
                    sum += fmaxf(acc[rt][ct][j] + bb[ct], 0.f);
            sum += __shfl_xor(sum, 16);
            sum += __shfl_xor(sum, 32);
            if (g4 == 0) {
                int n = w * 32 + ct * 16 + lane15;
                atomicAdd(&HgP[(t * 8 + (job & 7)) * HGd + n], sum);
            }
        }
    }
}

// ---------------- GRU input gates (folds 8-way Hg partials) ----------------
__global__ __launch_bounds__(768) void k_gi(const float* __restrict__ HgP,
        const float* __restrict__ WihT, const float* __restrict__ b_ih,
        float* __restrict__ gi_all) {
    __shared__ float x[HGd];
    int t = blockIdx.x, g = threadIdx.x;
    if (g < HGd) {
        float s = 0.f;
#pragma unroll
        for (int p = 0; p < 8; ++p) s += HgP[(t * 8 + p) * HGd + g];
        x[g] = s * INVN;
    }
    __syncthreads();
    float a = b_ih[g];
    for (int k = 0; k < HGd; ++k) a += WihT[k * 768 + g] * x[k];
    gi_all[t * 768 + g] = a;
}

// ---------------- multi-block GRU + head (lock-free grid sync) ----------------
__global__ __launch_bounds__(256) void k_gru_mb(const float* __restrict__ gi_all,
        const float* __restrict__ W_hh, const float* __restrict__ b_hh,
        const float* __restrict__ Wh1, const float* __restrict__ bh1,
        const float* __restrict__ Wh2, const float* __restrict__ bh2,
        float* __restrict__ gh, int* __restrict__ cnt, float* __restrict__ out) {
    int tid = threadIdx.x, b = blockIdx.x;
    int r_loc = tid >> 2, q = tid & 3;      // 64 rows/block, 4 threads/row
    int row = b * 64 + r_loc;               // 0..767

    // W_hh slice in registers: row, cols [q*64, q*64+64)
    float4 wv[16];
    {
        const float4* wr = reinterpret_cast<const float4*>(W_hh + (size_t)row * HTd + q * 64);
#pragma unroll
        for (int i = 0; i < 16; ++i) wv[i] = wr[i];
    }
    float bh = b_hh[row];

    __shared__ float h[HTd];
    if (tid < HTd) h[tid] = 0.0f;
    __syncthreads();

    for (int t = 0; t < T_STEPS; ++t) {
        float* ghp = gh + (t & 1) * 768;
        float s = 0.f;
#pragma unroll
        for (int i = 0; i < 16; ++i) {
            float4 hv = *reinterpret_cast<const float4*>(&h[q * 64 + i * 4]);
            s += wv[i].x * hv.x + wv[i].y * hv.y + wv[i].z * hv.z + wv[i].w * hv.w;
        }
        s += __shfl_xor(s, 1);
        s += __shfl_xor(s, 2);
        if (q == 0)
            __hip_atomic_store(&ghp[row], s + bh, __ATOMIC_RELAXED, __HIP_MEMORY_SCOPE_AGENT);
        __syncthreads();
        if (tid == 0) {
            __hip_atomic_fetch_add(cnt, 1, __ATOMIC_ACQ_REL, __HIP_MEMORY_SCOPE_AGENT);
            int target = GRU_BLOCKS * (t + 1);
            while (__hip_atomic_load(cnt, __ATOMIC_ACQUIRE, __HIP_MEMORY_SCOPE_AGENT) < target)
                __builtin_amdgcn_s_sleep(2);
        }
        __syncthreads();
        if (tid < HTd) {
            float ghr = __hip_atomic_load(&ghp[tid],         __ATOMIC_RELAXED, __HIP_MEMORY_SCOPE_AGENT);
            float ghz = __hip_atomic_load(&ghp[HTd + tid],   __ATOMIC_RELAXED, __HIP_MEMORY_SCOPE_AGENT);
            float ghn = __hip_atomic_load(&ghp[2*HTd + tid], __ATOMIC_RELAXED, __HIP_MEMORY_SCOPE_AGENT);
            float gir = gi_all[t * 768 + tid];
            float giz = gi_all[t * 768 + HTd + tid];
            float gin = gi_all[t * 768 + 2 * HTd + tid];
            float r = 1.0f / (1.0f + expf(-(gir + ghr)));
            float z = 1.0f / (1.0f + expf(-(giz + ghz)));
            float n = tanhf(gin + r * ghn);
            float hn = (1.0f - z) * n + z * h[tid];
            __syncthreads();
            h[tid] = hn;
        } else {
            __syncthreads();
        }
        __syncthreads();
    }

    if (b == 0) {
        __shared__ float act[64];
        if (tid < 64) {
            float a = bh1[tid];
            const float* wr = Wh1 + tid * HTd;
            for (int k = 0; k < HTd; ++k) a += wr[k] * h[k];
            act[tid] = fmaxf(a, 0.0f);
        }
        __syncthreads();
        if (tid == 0) {
            float y = bh2[0];
            for (int j = 0; j < 64; ++j) y += Wh2[j] * act[j];
            out[0] = y;
        }
    }
}

// ---------------- launch ----------------
extern "C" void kernel_launch(void* const* d_in, const int* in_sizes, int n_in,
                              void* d_out, int out_size, void* d_ws, size_t ws_size,
                              hipStream_t stream) {
    const float* x_seq = (const float*)d_in[0];
    const int*   ei    = (const int*)d_in[1];
    const float* W1l   = (const float*)d_in[2];
    const float* b1l   = (const float*)d_in[3];
    const float* W1r   = (const float*)d_in[4];
    const float* W2l   = (const float*)d_in[5];
    const float* b2l   = (const float*)d_in[6];
    const float* W2r   = (const float*)d_in[7];
    const float* W_ih  = (const float*)d_in[8];
    const float* W_hh  = (const float*)d_in[9];
    const float* b_ih  = (const float*)d_in[10];
    const float* b_hh  = (const float*)d_in[11];
    const float* Wh1   = (const float*)d_in[12];
    const float* bh1   = (const float*)d_in[13];
    const float* Wh2   = (const float*)d_in[14];
    const float* bh2   = (const float*)d_in[15];
    float* out = (float*)d_out;

    char* ws = (char*)d_ws;
    size_t off = 0;
    auto take = [&](size_t nbytes) -> void* {
        void* p = (void*)(ws + off);
        off += (nbytes + 255) & ~(size_t)255;
        return p;
    };
    int*    deg    = (int*)take(N_NODES * 4);
    int*    rp     = (int*)take((N_NODES + 1) * 4);
    int*    cursor = (int*)take(N_NODES * 4);
    int*    csr    = (int*)take(N_EDGES * 4);
    float*  invd   = (float*)take(N_NODES * 4);
    int*    perm   = (int*)take(N_NODES * 4);
    int*    bins   = (int*)take(256 * 4);
    int*    bincur = (int*)take(256 * 4);
    float*  Wc1    = (float*)take(32 * 128 * 4);
    ushort* WT2    = (ushort*)take(128 * 256 * 2);
    float*  WihT   = (float*)take(128 * 768 * 4);
    float*  HgP    = (float*)take(T_STEPS * 8 * HGd * 4);
    float*  gi_all = (float*)take(T_STEPS * 768 * 4);
    float*  gh     = (float*)take(2 * 768 * 4);
    int*    cnt    = (int*)take(256);
    int*    jobc   = (int*)take(32 * 4);

    const size_t slice = (size_t)N_NODES * HGd * 2;   // one timestep of h1 (bf16)
    int T_CH = 8;
    while (T_CH > 1 && off + (size_t)T_CH * ((slice + 255) & ~(size_t)255) > ws_size)
        T_CH >>= 1;
    ushort* h1u = (ushort*)take((size_t)T_CH * ((slice + 255) & ~(size_t)255));

    k_zero<<<256, 256, 0, stream>>>(deg, HgP, cnt, jobc, bins);
    k_degree<<<(N_EDGES + 255) / 256, 256, 0, stream>>>(ei, deg);
    k_scan<<<1, 1024, 0, stream>>>(deg, rp, cursor, invd);
    k_fill<<<(N_EDGES + 255) / 256, 256, 0, stream>>>(ei, cursor, csr);
    k_hist<<<(N_NODES + 255) / 256, 256, 0, stream>>>(deg, bins);
    k_binscan<<<1, 256, 0, stream>>>(bins, bincur);
    k_perm<<<(N_NODES + 255) / 256, 256, 0, stream>>>(deg, bincur, perm);
    {
        int total = 32 * 128 + 128 * 256 + 128 * 768;
        k_prepw<<<(total + 255) / 256, 256, 0, stream>>>(W1l, W1r, W2l, W2r, W_ih,
                                                         Wc1, WT2, WihT);
    }
    int chunk = 0;
    for (int t0 = 0; t0 < T_STEPS; t0 += T_CH, ++chunk) {
        int C = T_CH;
        k_sage1<<<1536, 256, 0, stream>>>(x_seq, rp, csr, invd, Wc1, b1l, perm, h1u,
                                          jobc + 2 * chunk, t0, C);
        k_sage2<<<1024, 256, 0, stream>>>(h1u, rp, csr, invd, WT2, b2l, perm, HgP,
                                          jobc + 2 * chunk + 1, t0, C);
    }
    k_gi<<<T_STEPS, 768, 0, stream>>>(HgP, WihT, b_ih, gi_all);
    k_gru_mb<<<GRU_BLOCKS, 256, 0, stream>>>(gi_all, W_hh, b_hh, Wh1, bh1, Wh2, bh2,
                                             gh, cnt, out);
}

// Round 5
// 2089.696 us; speedup vs baseline: 7.0049x; 1.4272x over previous
//
#include <hip/hip_runtime.h>
#include <hip/hip_bf16.h>

#define N_NODES 20000
#define N_EDGES 320000
#define T_STEPS 64
#define F_IN    16
#define HGd     128
#define HTd     256
#define INVN    (1.0f/20000.0f)
#define GRU_BLOCKS 4
#define NTILES   625            // 20000/32  (sage2 tiles)
#define S1_TILES 313            // ceil(20000/64)

typedef __attribute__((ext_vector_type(8))) short short8;
typedef __attribute__((ext_vector_type(4))) float f32x4;

static __device__ __forceinline__ ushort f2bf(float f) {
    __hip_bfloat16 b = __float2bfloat16(f);
    return *reinterpret_cast<ushort*>(&b);
}
static __device__ __forceinline__ float bflo(uint v) { return __uint_as_float(v << 16); }
static __device__ __forceinline__ float bfhi(uint v) { return __uint_as_float(v & 0xffff0000u); }

// ---------------- init ----------------
__global__ void k_zero(int* __restrict__ deg, float* __restrict__ HgP,
                       int* __restrict__ cnt, int* __restrict__ jobc,
                       int* __restrict__ bins) {
    int i = blockIdx.x * blockDim.x + threadIdx.x;
    if (i < N_NODES) deg[i] = 0;
    if (i < T_STEPS * 8 * HGd) HgP[i] = 0.0f;
    if (i == 0) *cnt = 0;
    if (i < 1024) jobc[i] = 0;
    if (i < 256) bins[i] = 0;
}

__global__ void k_degree(const int* __restrict__ ei, int* __restrict__ deg) {
    int e = blockIdx.x * blockDim.x + threadIdx.x;
    if (e < N_EDGES) atomicAdd(&deg[ei[N_EDGES + e]], 1);
}

__global__ __launch_bounds__(1024) void k_scan(const int* __restrict__ deg,
        int* __restrict__ rp, int* __restrict__ cursor, float* __restrict__ invd) {
    __shared__ int sh[1024];
    __shared__ int carry_s;
    int tid = threadIdx.x;
    if (tid == 0) { carry_s = 0; rp[0] = 0; }
    __syncthreads();
    for (int base = 0; base < N_NODES; base += 1024) {
        int i = base + tid;
        int v = (i < N_NODES) ? deg[i] : 0;
        sh[tid] = v;
        __syncthreads();
        for (int off = 1; off < 1024; off <<= 1) {
            int t = (tid >= off) ? sh[tid - off] : 0;
            __syncthreads();
            sh[tid] += t;
            __syncthreads();
        }
        int inc = sh[tid] + carry_s;
        if (i < N_NODES) {
            rp[i + 1] = inc;
            cursor[i] = inc - v;
            invd[i] = (v > 0) ? (1.0f / (float)v) : 0.0f;
        }
        __syncthreads();
        if (tid == 1023) carry_s = inc;
        __syncthreads();
    }
}

__global__ void k_fill(const int* __restrict__ ei, int* __restrict__ cursor,
                       int* __restrict__ csr) {
    int e = blockIdx.x * blockDim.x + threadIdx.x;
    if (e < N_EDGES) {
        int d = ei[N_EDGES + e];
        int p = atomicAdd(&cursor[d], 1);
        csr[p] = ei[e];
    }
}

// ---------------- degree-sort permutation (counting sort) ----------------
__global__ void k_hist(const int* __restrict__ deg, int* __restrict__ bins) {
    int i = blockIdx.x * blockDim.x + threadIdx.x;
    if (i < N_NODES) atomicAdd(&bins[min(deg[i], 255)], 1);
}

__global__ __launch_bounds__(256) void k_binscan(const int* __restrict__ bins,
                                                 int* __restrict__ bincur) {
    __shared__ int sh[256];
    int tid = threadIdx.x;
    sh[tid] = bins[tid];
    __syncthreads();
    for (int off = 1; off < 256; off <<= 1) {
        int v = (tid >= off) ? sh[tid - off] : 0;
        __syncthreads();
        sh[tid] += v;
        __syncthreads();
    }
    bincur[tid] = sh[tid] - bins[tid];   // exclusive prefix
}

__global__ void k_perm(const int* __restrict__ deg, int* __restrict__ bincur,
                       int* __restrict__ perm) {
    int i = blockIdx.x * blockDim.x + threadIdx.x;
    if (i < N_NODES) {
        int d = min(deg[i], 255);
        int p = atomicAdd(&bincur[d], 1);
        perm[p] = i;
    }
}

// ---------------- weight prep ----------------
__global__ void k_prepw(const float* __restrict__ W1l, const float* __restrict__ W1r,
                        const float* __restrict__ W2l, const float* __restrict__ W2r,
                        const float* __restrict__ W_ih,
                        float* __restrict__ Wc1, ushort* __restrict__ WT2,
                        float* __restrict__ WihT) {
    int i = blockIdx.x * blockDim.x + threadIdx.x;
    const int n1 = 32 * 128, n2 = 128 * 256, n3 = 128 * 768;
    if (i < n1) {
        int k = i >> 7, o = i & 127;
        Wc1[i] = (k < 16) ? W1l[o * 16 + k] : W1r[o * 16 + (k - 16)];
    } else if (i < n1 + n2) {
        int j = i - n1; int o = j >> 8, k = j & 255;
        float v = (k < 128) ? W2l[o * 128 + k] : W2r[o * 128 + (k - 128)];
        WT2[j] = f2bf(v);
    } else if (i < n1 + n2 + n3) {
        int j = i - n1 - n2; int k = j / 768, g = j % 768;
        WihT[j] = W_ih[g * 128 + k];
    }
}

// ---------------- SAGE layer 1 (per-XCD work-stealing, degree-sorted) ----------------
__global__ __launch_bounds__(256) void k_sage1(
        const float* __restrict__ x_seq, const int* __restrict__ rp,
        const int* __restrict__ csr, const float* __restrict__ invd,
        const float* __restrict__ Wc1, const float* __restrict__ b1l,
        const int* __restrict__ perm, ushort* __restrict__ h1u,
        int* __restrict__ jobc, int t0, int C) {
    __shared__ float u[64][32];
    __shared__ float w[32][128];
    __shared__ int pnode[64];
    __shared__ int job_s;
    int tid = threadIdx.x;
    const int ci = (blockIdx.x & 7) % C;       // this XCD's timestep slot
    int* ctr = jobc + ci;

    for (int i = tid; i < 32 * 128; i += 256) ((float*)w)[i] = Wc1[i];

    const float* xt = x_seq + (size_t)(t0 + ci) * N_NODES * F_IN;
    ushort* h1 = h1u + (size_t)ci * N_NODES * HGd;

    for (;;) {
        if (tid == 0) job_s = atomicAdd(ctr, 1);
        __syncthreads();                 // job ready; prior GEMM reads of u done
        int job = job_s;
        if (job >= S1_TILES) break;
        int nbase = job * 64;
        if (tid < 64) pnode[tid] = (nbase + tid < N_NODES) ? perm[nbase + tid] : -1;
        __syncthreads();

        { // aggregation: 4 threads per node, edge loop unrolled x4
            int n = tid >> 2, q = tid & 3;
            int node = pnode[n];
            float4 acc = make_float4(0, 0, 0, 0);
            float4 root = make_float4(0, 0, 0, 0);
            if (node >= 0) {
                int s = rp[node], e = rp[node + 1];
                int j = s;
                for (; j + 4 <= e; j += 4) {
                    int i0 = csr[j], i1 = csr[j + 1], i2 = csr[j + 2], i3 = csr[j + 3];
                    float4 v0 = *reinterpret_cast<const float4*>(xt + i0 * F_IN + q * 4);
                    float4 v1 = *reinterpret_cast<const float4*>(xt + i1 * F_IN + q * 4);
                    float4 v2 = *reinterpret_cast<const float4*>(xt + i2 * F_IN + q * 4);
                    float4 v3 = *reinterpret_cast<const float4*>(xt + i3 * F_IN + q * 4);
                    acc.x += v0.x + v1.x + v2.x + v3.x;
                    acc.y += v0.y + v1.y + v2.y + v3.y;
                    acc.z += v0.z + v1.z + v2.z + v3.z;
                    acc.w += v0.w + v1.w + v2.w + v3.w;
                }
                for (; j < e; ++j) {
                    int sn = csr[j];
                    float4 v = *reinterpret_cast<const float4*>(xt + sn * F_IN + q * 4);
                    acc.x += v.x; acc.y += v.y; acc.z += v.z; acc.w += v.w;
                }
                float id = invd[node];
                acc.x *= id; acc.y *= id; acc.z *= id; acc.w *= id;
                root = *reinterpret_cast<const float4*>(xt + node * F_IN + q * 4);
            }
            *reinterpret_cast<float4*>(&u[n][q * 4]) = acc;
            *reinterpret_cast<float4*>(&u[n][16 + q * 4]) = root;
        }
        __syncthreads();

        // GEMM [64 x 32] @ [32 x 128]; thread tile 8 nodes x 4 outs
        int og = tid & 31, ng = tid >> 5;
        int o = og * 4;
        float acc[8][4];
#pragma unroll
        for (int j = 0; j < 8; ++j)
#pragma unroll
            for (int c = 0; c < 4; ++c) acc[j][c] = 0.0f;

#pragma unroll
        for (int k = 0; k < 32; k += 4) {
            float4 w0 = *reinterpret_cast<const float4*>(&w[k + 0][o]);
            float4 w1 = *reinterpret_cast<const float4*>(&w[k + 1][o]);
            float4 w2 = *reinterpret_cast<const float4*>(&w[k + 2][o]);
            float4 w3 = *reinterpret_cast<const float4*>(&w[k + 3][o]);
#pragma unroll
            for (int j = 0; j < 8; ++j) {
                float4 uv = *reinterpret_cast<const float4*>(&u[ng * 8 + j][k]);
                acc[j][0] += uv.x * w0.x + uv.y * w1.x + uv.z * w2.x + uv.w * w3.x;
                acc[j][1] += uv.x * w0.y + uv.y * w1.y + uv.z * w2.y + uv.w * w3.y;
                acc[j][2] += uv.x * w0.z + uv.y * w1.z + uv.z * w2.z + uv.w * w3.z;
                acc[j][3] += uv.x * w0.w + uv.y * w1.w + uv.z * w2.w + uv.w * w3.w;
            }
        }

        float4 bv = *reinterpret_cast<const float4*>(b1l + o);
#pragma unroll
        for (int j = 0; j < 8; ++j) {
            int node = pnode[ng * 8 + j];
            if (node >= 0) {
                float rx = fmaxf(acc[j][0] + bv.x, 0.0f);
                float ry = fmaxf(acc[j][1] + bv.y, 0.0f);
                float rz = fmaxf(acc[j][2] + bv.z, 0.0f);
                float rw = fmaxf(acc[j][3] + bv.w, 0.0f);
                uint2 pk;
                pk.x = (uint)f2bf(rx) | ((uint)f2bf(ry) << 16);
                pk.y = (uint)f2bf(rz) | ((uint)f2bf(rw) << 16);
                *reinterpret_cast<uint2*>(h1 + (size_t)node * HGd + o) = pk;
            }
        }
    }
}

// ---------------- SAGE layer 2 (bf16 MFMA, per-XCD work-stealing) ----------------
__global__ __launch_bounds__(256) void k_sage2(
        const ushort* __restrict__ h1u, const int* __restrict__ rp,
        const int* __restrict__ csr, const float* __restrict__ invd,
        const ushort* __restrict__ WT2, const float* __restrict__ b2l,
        const int* __restrict__ perm, float* __restrict__ HgP,
        int* __restrict__ jobc, int t0, int C) {
    __shared__ uint4 usm4[32 * 512 / 16];   // 16 KB
    __shared__ int pnode[32];
    __shared__ int job_s;
    char* ub = (char*)usm4;
    int tid = threadIdx.x;
    int l = tid & 63, w = tid >> 6;
    int lane15 = l & 15, g4 = l >> 4;
    const int ci = (blockIdx.x & 7) % C;
    int* ctr = jobc + ci;
    int t = t0 + ci;
    const ushort* h1 = h1u + (size_t)ci * N_NODES * HGd;

    // B-fragment preload: wave w owns cols [w*32, w*32+32)
    short8 bfr[2][8];
    float bb[2];
#pragma unroll
    for (int ct = 0; ct < 2; ++ct) {
        int n = w * 32 + ct * 16 + lane15;
        const ushort* bp = WT2 + n * 256 + g4 * 8;
#pragma unroll
        for (int ks = 0; ks < 8; ++ks)
            bfr[ct][ks] = *reinterpret_cast<const short8*>(bp + ks * 32);
        bb[ct] = b2l[n];
    }

    for (;;) {
        if (tid == 0) job_s = atomicAdd(ctr, 1);
        __syncthreads();                 // job ready; prior MFMA LDS reads done
        int job = job_s;
        if (job >= NTILES) break;
        int nbase = job * 32;
        if (tid < 32) pnode[tid] = perm[nbase + tid];
        __syncthreads();

        // root rows: block-cooperative copy, 512 x 16B
        for (int i = tid; i < 512; i += 256) {
            int nl = i >> 4, seg = i & 15;
            uint4 v = *reinterpret_cast<const uint4*>(h1 + (size_t)pnode[nl] * HGd + seg * 8);
            *reinterpret_cast<uint4*>(ub + ((nl * 512 + 256 + seg * 16) ^ ((nl & 7) << 4))) = v;
        }

        // gather: wave w -> 8 nodes in 2 passes of 4; 16 lanes/node; edges x4 unrolled
#pragma unroll
        for (int g = 0; g < 2; ++g) {
            int nl = w * 8 + g * 4 + g4;
            int node = pnode[nl];
            int s = rp[node], e = rp[node + 1];
            float af[8] = {0, 0, 0, 0, 0, 0, 0, 0};
            int j = s;
            for (; j + 4 <= e; j += 4) {
                int i0 = csr[j], i1 = csr[j + 1], i2 = csr[j + 2], i3 = csr[j + 3];
                uint4 v0 = *reinterpret_cast<const uint4*>(h1 + (size_t)i0 * HGd + lane15 * 8);
                uint4 v1 = *reinterpret_cast<const uint4*>(h1 + (size_t)i1 * HGd + lane15 * 8);
                uint4 v2 = *reinterpret_cast<const uint4*>(h1 + (size_t)i2 * HGd + lane15 * 8);
                uint4 v3 = *reinterpret_cast<const uint4*>(h1 + (size_t)i3 * HGd + lane15 * 8);
                af[0] += bflo(v0.x) + bflo(v1.x) + bflo(v2.x) + bflo(v3.x);
                af[1] += bfhi(v0.x) + bfhi(v1.x) + bfhi(v2.x) + bfhi(v3.x);
                af[2] += bflo(v0.y) + bflo(v1.y) + bflo(v2.y) + bflo(v3.y);
                af[3] += bfhi(v0.y) + bfhi(v1.y) + bfhi(v2.y) + bfhi(v3.y);
                af[4] += bflo(v0.z) + bflo(v1.z) + bflo(v2.z) + bflo(v3.z);
                af[5] += bfhi(v0.z) + bfhi(v1.z) + bfhi(v2.z) + bfhi(v3.z);
                af[6] += bflo(v0.w) + bflo(v1.w) + bflo(v2.w) + bflo(v3.w);
                af[7] += bfhi(v0.w) + bfhi(v1.w) + bfhi(v2.w) + bfhi(v3.w);
            }
            for (; j < e; ++j) {
                int sn = csr[j];
                uint4 v = *reinterpret_cast<const uint4*>(h1 + (size_t)sn * HGd + lane15 * 8);
                af[0] += bflo(v.x); af[1] += bfhi(v.x);
                af[2] += bflo(v.y); af[3] += bfhi(v.y);
                af[4] += bflo(v.z); af[5] += bfhi(v.z);
                af[6] += bflo(v.w); af[7] += bfhi(v.w);
            }
            float id = invd[node];
            uint4 pk;
            pk.x = (uint)f2bf(af[0] * id) | ((uint)f2bf(af[1] * id) << 16);
            pk.y = (uint)f2bf(af[2] * id) | ((uint)f2bf(af[3] * id) << 16);
            pk.z = (uint)f2bf(af[4] * id) | ((uint)f2bf(af[5] * id) << 16);
            pk.w = (uint)f2bf(af[6] * id) | ((uint)f2bf(af[7] * id) << 16);
            *reinterpret_cast<uint4*>(ub + ((nl * 512 + lane15 * 16) ^ ((nl & 7) << 4))) = pk;
        }
        __syncthreads();

        // MFMA: [32 x 256] @ WT2^T -> [32 x 128]; wave w cols w*32..+31
        f32x4 acc[2][2];
#pragma unroll
        for (int rt = 0; rt < 2; ++rt)
#pragma unroll
            for (int ct = 0; ct < 2; ++ct) acc[rt][ct] = (f32x4)(0.0f);

#pragma unroll
        for (int ks = 0; ks < 8; ++ks) {
#pragma unroll
            for (int rt = 0; rt < 2; ++rt) {
                int row = rt * 16 + lane15;
                int byt = (row * 512 + (ks * 32 + g4 * 8) * 2) ^ ((row & 7) << 4);
                short8 af = *reinterpret_cast<const short8*>(ub + byt);
                acc[rt][0] = __builtin_amdgcn_mfma_f32_16x16x32_bf16(af, bfr[0][ks], acc[rt][0], 0, 0, 0);
                acc[rt][1] = __builtin_amdgcn_mfma_f32_16x16x32_bf16(af, bfr[1][ks], acc[rt][1], 0, 0, 0);
            }
        }

        // bias + relu + column sums over 32 nodes -> atomic flush per tile
#pragma unroll
        for (int ct = 0; ct < 2; ++ct) {
            float sum = 0.f;
#pragma unroll
            for (int rt = 0; rt < 2; ++rt)
#pragma unroll
                for (int j = 0; j < 4; ++j)
                    sum += fmaxf(acc[rt][ct][j] + bb[ct], 0.f);
            sum += __shfl_xor(sum, 16);
            sum += __shfl_xor(sum, 32);
            if (g4 == 0) {
                int n = w * 32 + ct * 16 + lane15;
                atomicAdd(&HgP[(t * 8 + (job & 7)) * HGd + n], sum);
            }
        }
    }
}

// ---------------- GRU input gates (folds 8-way Hg partials) ----------------
__global__ __launch_bounds__(768) void k_gi(const float* __restrict__ HgP,
        const float* __restrict__ WihT, const float* __restrict__ b_ih,
        float* __restrict__ gi_all) {
    __shared__ float x[HGd];
    int t = blockIdx.x, g = threadIdx.x;
    if (g < HGd) {
        float s = 0.f;
#pragma unroll
        for (int p = 0; p < 8; ++p) s += HgP[(t * 8 + p) * HGd + g];
        x[g] = s * INVN;
    }
    __syncthreads();
    float a = b_ih[g];
    for (int k = 0; k < HGd; ++k) a += WihT[k * 768 + g] * x[k];
    gi_all[t * 768 + g] = a;
}

// ---------------- multi-block GRU + head (4 blocks x 768 thr) ----------------
__global__ __launch_bounds__(768) void k_gru_mb(const float* __restrict__ gi_all,
        const float* __restrict__ W_hh, const float* __restrict__ b_hh,
        const float* __restrict__ Wh1, const float* __restrict__ bh1,
        const float* __restrict__ Wh2, const float* __restrict__ bh2,
        float* __restrict__ gh, int* __restrict__ cnt, float* __restrict__ out) {
    int tid = threadIdx.x, b = blockIdx.x;
    int r_loc = tid >> 2, q = tid & 3;      // 192 rows/block, 4 threads/row
    int row = b * 192 + r_loc;              // 0..767

    // W_hh slice in registers: row, cols [q*64, q*64+64)
    float4 wv[16];
    {
        const float4* wr = reinterpret_cast<const float4*>(W_hh + (size_t)row * HTd + q * 64);
#pragma unroll
        for (int i = 0; i < 16; ++i) wv[i] = wr[i];
    }
    float bh = b_hh[row];

    __shared__ float h[HTd];
    if (tid < HTd) h[tid] = 0.0f;
    __syncthreads();

    for (int t = 0; t < T_STEPS; ++t) {
        float* ghp = gh + (t & 1) * 768;
        float s = 0.f;
#pragma unroll
        for (int i = 0; i < 16; ++i) {
            float4 hv = *reinterpret_cast<const float4*>(&h[q * 64 + i * 4]);
            s += wv[i].x * hv.x + wv[i].y * hv.y + wv[i].z * hv.z + wv[i].w * hv.w;
        }
        s += __shfl_xor(s, 1);
        s += __shfl_xor(s, 2);
        if (q == 0)
            __hip_atomic_store(&ghp[row], s + bh, __ATOMIC_RELAXED, __HIP_MEMORY_SCOPE_AGENT);
        __syncthreads();
        if (tid == 0) {
            __hip_atomic_fetch_add(cnt, 1, __ATOMIC_ACQ_REL, __HIP_MEMORY_SCOPE_AGENT);
            int target = GRU_BLOCKS * (t + 1);
            while (__hip_atomic_load(cnt, __ATOMIC_ACQUIRE, __HIP_MEMORY_SCOPE_AGENT) < target)
                __builtin_amdgcn_s_sleep(2);
        }
        __syncthreads();
        if (tid < HTd) {
            float ghr = __hip_atomic_load(&ghp[tid],         __ATOMIC_RELAXED, __HIP_MEMORY_SCOPE_AGENT);
            float ghz = __hip_atomic_load(&ghp[HTd + tid],   __ATOMIC_RELAXED, __HIP_MEMORY_SCOPE_AGENT);
            float ghn = __hip_atomic_load(&ghp[2*HTd + tid], __ATOMIC_RELAXED, __HIP_MEMORY_SCOPE_AGENT);
            float gir = gi_all[t * 768 + tid];
            float giz = gi_all[t * 768 + HTd + tid];
            float gin = gi_all[t * 768 + 2 * HTd + tid];
            float r = 1.0f / (1.0f + expf(-(gir + ghr)));
            float z = 1.0f / (1.0f + expf(-(giz + ghz)));
            float n = tanhf(gin + r * ghn);
            float hn = (1.0f - z) * n + z * h[tid];
            __syncthreads();
            h[tid] = hn;
        } else {
            __syncthreads();
        }
        __syncthreads();
    }

    if (b == 0) {
        __shared__ float act[64];
        if (tid < 64) {
            float a = bh1[tid];
            const float* wr = Wh1 + tid * HTd;
            for (int k = 0; k < HTd; ++k) a += wr[k] * h[k];
            act[tid] = fmaxf(a, 0.0f);
        }
        __syncthreads();
        if (tid == 0) {
            float y = bh2[0];
            for (int j = 0; j < 64; ++j) y += Wh2[j] * act[j];
            out[0] = y;
        }
    }
}

// ---------------- launch ----------------
extern "C" void kernel_launch(void* const* d_in, const int* in_sizes, int n_in,
                              void* d_out, int out_size, void* d_ws, size_t ws_size,
                              hipStream_t stream) {
    const float* x_seq = (const float*)d_in[0];
    const int*   ei    = (const int*)d_in[1];
    const float* W1l   = (const float*)d_in[2];
    const float* b1l   = (const float*)d_in[3];
    const float* W1r   = (const float*)d_in[4];
    const float* W2l   = (const float*)d_in[5];
    const float* b2l   = (const float*)d_in[6];
    const float* W2r   = (const float*)d_in[7];
    const float* W_ih  = (const float*)d_in[8];
    const float* W_hh  = (const float*)d_in[9];
    const float* b_ih  = (const float*)d_in[10];
    const float* b_hh  = (const float*)d_in[11];
    const float* Wh1   = (const float*)d_in[12];
    const float* bh1   = (const float*)d_in[13];
    const float* Wh2   = (const float*)d_in[14];
    const float* bh2   = (const float*)d_in[15];
    float* out = (float*)d_out;

    char* ws = (char*)d_ws;
    size_t off = 0;
    auto take = [&](size_t nbytes) -> void* {
        void* p = (void*)(ws + off);
        off += (nbytes + 255) & ~(size_t)255;
        return p;
    };
    int*    deg    = (int*)take(N_NODES * 4);
    int*    rp     = (int*)take((N_NODES + 1) * 4);
    int*    cursor = (int*)take(N_NODES * 4);
    int*    csr    = (int*)take(N_EDGES * 4);
    float*  invd   = (float*)take(N_NODES * 4);
    int*    perm   = (int*)take(N_NODES * 4);
    int*    bins   = (int*)take(256 * 4);
    int*    bincur = (int*)take(256 * 4);
    float*  Wc1    = (float*)take(32 * 128 * 4);
    ushort* WT2    = (ushort*)take(128 * 256 * 2);
    float*  WihT   = (float*)take(128 * 768 * 4);
    float*  HgP    = (float*)take(T_STEPS * 8 * HGd * 4);
    float*  gi_all = (float*)take(T_STEPS * 768 * 4);
    float*  gh     = (float*)take(2 * 768 * 4);
    int*    cnt    = (int*)take(256);
    int*    jobc   = (int*)take(1024 * 4);

    const size_t slice = (size_t)N_NODES * HGd * 2;   // one timestep of h1 (bf16)
    int T_CH = 8;
    while (T_CH > 1 && off + (size_t)T_CH * ((slice + 255) & ~(size_t)255) > ws_size)
        T_CH >>= 1;
    ushort* h1u = (ushort*)take((size_t)T_CH * ((slice + 255) & ~(size_t)255));

    k_zero<<<256, 256, 0, stream>>>(deg, HgP, cnt, jobc, bins);
    k_degree<<<(N_EDGES + 255) / 256, 256, 0, stream>>>(ei, deg);
    k_scan<<<1, 1024, 0, stream>>>(deg, rp, cursor, invd);
    k_fill<<<(N_EDGES + 255) / 256, 256, 0, stream>>>(ei, cursor, csr);
    k_hist<<<(N_NODES + 255) / 256, 256, 0, stream>>>(deg, bins);
    k_binscan<<<1, 256, 0, stream>>>(bins, bincur);
    k_perm<<<(N_NODES + 255) / 256, 256, 0, stream>>>(deg, bincur, perm);
    {
        int total = 32 * 128 + 128 * 256 + 128 * 768;
        k_prepw<<<(total + 255) / 256, 256, 0, stream>>>(W1l, W1r, W2l, W2r, W_ih,
                                                         Wc1, WT2, WihT);
    }
    int chunk = 0;
    for (int t0 = 0; t0 < T_STEPS; t0 += T_CH, ++chunk) {
        int C = T_CH;
        k_sage1<<<2048, 256, 0, stream>>>(x_seq, rp, csr, invd, Wc1, b1l, perm, h1u,
                                          jobc + chunk * 16, t0, C);
        k_sage2<<<2048, 256, 0, stream>>>(h1u, rp, csr, invd, WT2, b2l, perm, HgP,
                                          jobc + chunk * 16 + 8, t0, C);
    }
    k_gi<<<T_STEPS, 768, 0, stream>>>(HgP, WihT, b_ih, gi_all);
    k_gru_mb<<<GRU_BLOCKS, 768, 0, stream>>>(gi_all, W_hh, b_hh, Wh1, bh1, Wh2, bh2,
                                             gh, cnt, out);
}